// Round 10
// baseline (126.097 us; speedup 1.0000x reference)
//
#include <hip/hip_runtime.h>
#include <hip/hip_bf16.h>
#include <stdint.h>

#define B_   4
#define SEQ_ 1024
#define DM   1024
#define H_   16
#define HD   64

typedef __bf16 bf16;
typedef __bf16 bf16x8 __attribute__((ext_vector_type(8)));
typedef __bf16 bf16x4v __attribute__((ext_vector_type(4)));
typedef __bf16 bf16x2 __attribute__((ext_vector_type(2)));
typedef float  f32x4 __attribute__((ext_vector_type(4)));

__device__ __forceinline__ void gl_lds16(const void* g, void* s_uniform) {
    __builtin_amdgcn_global_load_lds(
        (const __attribute__((address_space(1))) uint32_t*)g,
        (__attribute__((address_space(3))) uint32_t*)s_uniform,
        16, 0, 0);
}

// ---------------------------------------------------------------------------
// prep: fp32 -> bf16 casts + T5 relative-position bias table [h][dist]
// ---------------------------------------------------------------------------
__global__ __launch_bounds__(256) void prep_kernel(
    const float* __restrict__ x, const float* __restrict__ Wq,
    const float* __restrict__ Wk, const float* __restrict__ Wv,
    const float* __restrict__ Wo, const float* __restrict__ rel,
    bf16* __restrict__ xb, bf16* __restrict__ wqkvb, bf16* __restrict__ wob,
    float* __restrict__ biasT)
{
    int tid = blockIdx.x * 256 + threadIdx.x;
    int stride = gridDim.x * 256;

    for (int i = tid; i < (B_*SEQ_*DM)/4; i += stride) {
        float4 v = ((const float4*)x)[i];
        bf16x4v o; o[0]=(bf16)v.x; o[1]=(bf16)v.y; o[2]=(bf16)v.z; o[3]=(bf16)v.w;
        ((bf16x4v*)xb)[i] = o;
    }
    for (int i = tid; i < (3*DM*DM)/4; i += stride) {
        int n = i >> 8, k4 = i & 255;
        const float* src = (n < 1024) ? Wq : (n < 2048) ? Wk : Wv;
        float4 v = ((const float4*)(src + (size_t)(n & 1023) * DM))[k4];
        bf16x4v o; o[0]=(bf16)v.x; o[1]=(bf16)v.y; o[2]=(bf16)v.z; o[3]=(bf16)v.w;
        ((bf16x4v*)wqkvb)[i] = o;
    }
    for (int i = tid; i < (DM*DM)/4; i += stride) {
        float4 v = ((const float4*)Wo)[i];
        bf16x4v o; o[0]=(bf16)v.x; o[1]=(bf16)v.y; o[2]=(bf16)v.z; o[3]=(bf16)v.w;
        ((bf16x4v*)wob)[i] = o;
    }
    for (int i = tid; i < H_ * SEQ_; i += stride) {
        int h = i >> 10, dist = i & 1023;
        int bkt;
        if (dist < 16) {
            bkt = dist;
        } else {
            float r = logf((float)dist * (1.0f/16.0f)) / logf(8.0f) * 16.0f;
            int vb = 16 + (int)r;
            bkt = vb > 31 ? 31 : vb;
        }
        biasT[i] = rel[bkt * H_ + h] * 0.125f;
    }
}

// ---------------------------------------------------------------------------
// Ring GEMM (QKV): C = A @ B^T, BM=BN=128, BK=32, 256 thr (4 waves 2x2),
// 3 LDS buffers, depth-2 prefetch, counted vmcnt(4), chunk-XOR swizzle.
// Rectangle XCD swizzle. Q/K direct scatter; V via LDS transpose.
// ---------------------------------------------------------------------------
template<int NT>
__global__ __launch_bounds__(256, 3) void gemm_ring(
    const bf16* __restrict__ Ag, const bf16* __restrict__ Bg,
    bf16* __restrict__ qb, bf16* __restrict__ kb, bf16* __restrict__ vtb,
    const float* __restrict__ bq, const float* __restrict__ bk,
    const float* __restrict__ bv)
{
    __shared__ __align__(16) bf16 tile[3][256 * 32];   // 3 x 16 KB

    const int t = threadIdx.x;
    const int lane = t & 63, w = t >> 6;
    const int wr = w >> 1, wc = w & 1;
    const int row_l = lane & 15;
    const int lg = lane >> 4;

    int xcd = blockIdx.x & 7;
    int idx = blockIdx.x >> 3;
    int ty = (xcd >> 1) * 8 + idx / 12;
    int tx = (xcd & 1) * 12 + idx % 12;
    const int m0 = ty * 128, n0 = tx * 128;

    f32x4 acc[4][4] = {};

    auto STAGE = [&](int buf, int kt) {
        bf16* dst = &tile[buf][0];
        #pragma unroll
        for (int i = 0; i < 4; ++i) {
            int e = i * 2048 + t * 8;
            int r = e >> 5;
            int csw = ((t & 3) ^ (r & 3)) << 3;
            const bf16* src = (r < 128)
                ? (Ag + (long)(m0 + r) * 1024 + kt * 32 + csw)
                : (Bg + (long)(n0 + r - 128) * 1024 + kt * 32 + csw);
            gl_lds16(src, dst + i * 2048 + w * 512);
        }
    };

    auto COMPUTE = [&](int buf) {
        const bf16* bp = &tile[buf][0];
        bf16x8 af[4], bfr[4];
        #pragma unroll
        for (int m = 0; m < 4; ++m) {
            int ra = wr * 64 + m * 16 + row_l;
            af[m] = *(const bf16x8*)&bp[ra * 32 + ((lg ^ (ra & 3)) << 3)];
        }
        #pragma unroll
        for (int n = 0; n < 4; ++n) {
            int rb = 128 + wc * 64 + n * 16 + row_l;
            bfr[n] = *(const bf16x8*)&bp[rb * 32 + ((lg ^ (rb & 3)) << 3)];
        }
        #pragma unroll
        for (int m = 0; m < 4; ++m)
            #pragma unroll
            for (int n = 0; n < 4; ++n)
                acc[m][n] = __builtin_amdgcn_mfma_f32_16x16x32_bf16(
                    af[m], bfr[n], acc[m][n], 0, 0, 0);
    };

    STAGE(0, 0); STAGE(1, 1);
    asm volatile("s_waitcnt vmcnt(4)" ::: "memory");
    __builtin_amdgcn_s_barrier();

    int cb = 0;
    for (int kt = 0; kt < NT; ++kt) {
        int sb = cb - 1; if (sb < 0) sb += 3;
        if (kt + 2 < NT) STAGE(sb, kt + 2);
        COMPUTE(cb);
        if (kt + 2 < NT) { asm volatile("s_waitcnt vmcnt(4)" ::: "memory"); }
        else             { asm volatile("s_waitcnt vmcnt(0)" ::: "memory"); }
        __builtin_amdgcn_s_barrier();
        cb = (cb + 1 == 3) ? 0 : cb + 1;
    }

    const int rbase = (lane >> 4) * 4;

    if (n0 < 2048) {
        #pragma unroll
        for (int m = 0; m < 4; ++m) {
            #pragma unroll
            for (int n = 0; n < 4; ++n) {
                #pragma unroll
                for (int g = 0; g < 4; ++g) {
                    int gm = m0 + wr * 64 + m * 16 + rbase + g;
                    int gn = n0 + wc * 64 + n * 16 + row_l;
                    int which = gn >> 10, nn = gn & 1023;
                    int h = nn >> 6, d = nn & 63;
                    int b = gm >> 10, s = gm & 1023;
                    float v = acc[m][n][g] + ((which == 0) ? bq[nn] : bk[nn]);
                    bf16 bv16 = (bf16)v;
                    if (which == 0)
                        qb[((long)(b*H_ + h)*SEQ_ + s)*HD + d] = bv16;
                    else
                        kb[((long)(b*H_ + h)*SEQ_ + s)*HD + d] = bv16;
                }
            }
        }
    } else {
        // V epilogue: LDS transpose (XOR-staggered) -> coalesced Vt stores
        bf16* lt = &tile[0][0];
        #pragma unroll
        for (int m = 0; m < 4; ++m) {
            #pragma unroll
            for (int n = 0; n < 4; ++n) {
                int nl = wc * 64 + n * 16 + row_l;
                int mlb = wr * 64 + m * 16 + rbase;
                float bvv = bv[(n0 & 1023) + nl];
                #pragma unroll
                for (int g2 = 0; g2 < 2; ++g2) {
                    bf16x2 pk;
                    pk[0] = (bf16)(acc[m][n][2*g2]     + bvv);
                    pk[1] = (bf16)(acc[m][n][2*g2 + 1] + bvv);
                    int ml = mlb + 2 * g2;
                    int byte = nl * 256 + ((ml * 2) ^ ((nl & 15) << 4));
                    *(bf16x2*)((char*)lt + byte) = pk;
                }
            }
        }
        __syncthreads();
        {
            int nl = t >> 1, sc = t & 1;
            int nn = (n0 & 1023) + nl;
            int h = nn >> 6, d = nn & 63;
            int b = m0 >> 10, s0 = (m0 & 1023) + sc * 64;
            bf16* dst = vtb + ((long)(b*H_ + h)*HD + d)*SEQ_ + s0;
            #pragma unroll
            for (int i = 0; i < 8; ++i) {
                int byte = nl * 256 + ((sc * 128 + i * 16) ^ ((nl & 15) << 4));
                *(float4*)(dst + i * 8) = *(const float4*)((char*)lt + byte);
            }
        }
    }
}

// ---------------------------------------------------------------------------
// Ring GEMM (out-proj): BM=128, BN=64, BK=32, 3 bufs, counted vmcnt.
// ---------------------------------------------------------------------------
template<int NT>
__global__ __launch_bounds__(256, 2) void gemm_ring_o(
    const bf16* __restrict__ Ag, const bf16* __restrict__ Bg,
    float* __restrict__ outp, const float* __restrict__ bo)
{
    __shared__ __align__(16) bf16 tile[3][192 * 32];

    const int t = threadIdx.x;
    const int lane = t & 63, w = t >> 6;
    const int wr = w >> 1, wc = w & 1;
    const int row_l = lane & 15;
    const int lg = lane >> 4;

    int xcd = blockIdx.x & 7;
    int idx = blockIdx.x >> 3;
    int ty = (xcd >> 1) * 8 + (idx >> 3);
    int tx = (xcd & 1) * 8 + (idx & 7);
    const int m0 = ty * 128, n0 = tx * 64;

    f32x4 acc[4][2] = {};

    auto STAGE = [&](int buf, int kt) {
        bf16* dst = &tile[buf][0];
        #pragma unroll
        for (int i = 0; i < 3; ++i) {
            int e = i * 2048 + t * 8;
            int r = e >> 5;
            int csw = ((t & 3) ^ (r & 3)) << 3;
            const bf16* src = (r < 128)
                ? (Ag + (long)(m0 + r) * 1024 + kt * 32 + csw)
                : (Bg + (long)(n0 + r - 128) * 1024 + kt * 32 + csw);
            gl_lds16(src, dst + i * 2048 + w * 512);
        }
    };

    auto COMPUTE = [&](int buf) {
        const bf16* bp = &tile[buf][0];
        bf16x8 af[4], bfr[2];
        #pragma unroll
        for (int m = 0; m < 4; ++m) {
            int ra = wr * 64 + m * 16 + row_l;
            af[m] = *(const bf16x8*)&bp[ra * 32 + ((lg ^ (ra & 3)) << 3)];
        }
        #pragma unroll
        for (int n = 0; n < 2; ++n) {
            int rb = 128 + wc * 32 + n * 16 + row_l;
            bfr[n] = *(const bf16x8*)&bp[rb * 32 + ((lg ^ (rb & 3)) << 3)];
        }
        #pragma unroll
        for (int m = 0; m < 4; ++m)
            #pragma unroll
            for (int n = 0; n < 2; ++n)
                acc[m][n] = __builtin_amdgcn_mfma_f32_16x16x32_bf16(
                    af[m], bfr[n], acc[m][n], 0, 0, 0);
    };

    STAGE(0, 0); STAGE(1, 1);
    asm volatile("s_waitcnt vmcnt(3)" ::: "memory");
    __builtin_amdgcn_s_barrier();

    int cb = 0;
    for (int kt = 0; kt < NT; ++kt) {
        int sb = cb - 1; if (sb < 0) sb += 3;
        if (kt + 2 < NT) STAGE(sb, kt + 2);
        COMPUTE(cb);
        if (kt + 2 < NT) { asm volatile("s_waitcnt vmcnt(3)" ::: "memory"); }
        else             { asm volatile("s_waitcnt vmcnt(0)" ::: "memory"); }
        __builtin_amdgcn_s_barrier();
        cb = (cb + 1 == 3) ? 0 : cb + 1;
    }

    const int rbase = (lane >> 4) * 4;
    #pragma unroll
    for (int m = 0; m < 4; ++m) {
        #pragma unroll
        for (int n = 0; n < 2; ++n) {
            #pragma unroll
            for (int g = 0; g < 4; ++g) {
                int gm = m0 + wr * 64 + m * 16 + rbase + g;
                int gn = n0 + wc * 32 + n * 16 + row_l;
                outp[(long)gm * DM + gn] = acc[m][n][g] + bo[gn];
            }
        }
    }
}

// ---------------------------------------------------------------------------
// Flash attention v5: register-direct K/V (no LDS staging, L2-resident via
// XCD-localized groups), causal pairing, static-shift softmax, ZERO in-loop
// barriers (Ps is per-wave). grid 512.
// ---------------------------------------------------------------------------
#define PSTRIDE 72

__global__ __launch_bounds__(256, 2) void attn_kernel(
    const bf16* __restrict__ Qb, const bf16* __restrict__ Kb,
    const bf16* __restrict__ Vtb, const float* __restrict__ biasT,
    bf16* __restrict__ AO)
{
    __shared__ __align__(16) bf16 Ps[4][16 * PSTRIDE];
    __shared__ float biasS[SEQ_];

    int t = threadIdx.x;
    int lane = t & 63, w = t >> 6;

    int bid = blockIdx.x;
    int xcd = bid & 7;
    int widx = bid >> 3;
    int g = xcd * 8 + (widx >> 3);
    int pair = widx & 7;
    int qt_lo = pair, qt_hi = 15 - pair;
    int h = g & 15, b = g >> 4;

    int row_l = lane & 15;
    int ksl = (lane >> 4) * 8;
    int rbase = (lane >> 4) * 4;

    ((float4*)biasS)[t] = ((const float4*)(biasT + (long)h * SEQ_))[t];
    __syncthreads();                 // the only block-wide barrier

    const bf16* Kbase = Kb + (long)g * SEQ_ * HD;
    const bf16* Vbase = Vtb + (long)g * HD * SEQ_;

    const bf16* QpA = Qb + ((long)g * SEQ_ + qt_lo * 64 + w * 16) * HD;
    const bf16* QpB = Qb + ((long)g * SEQ_ + qt_hi * 64 + w * 16) * HD;
    bf16x8 qA0 = *(const bf16x8*)&QpA[row_l * HD + ksl];
    bf16x8 qA1 = *(const bf16x8*)&QpA[row_l * HD + 32 + ksl];
    bf16x8 qB0 = *(const bf16x8*)&QpB[row_l * HD + ksl];
    bf16x8 qB1 = *(const bf16x8*)&QpB[row_l * HD + 32 + ksl];

    f32x4 oaccA[4] = {}, oaccB[4] = {};
    float lA[4] = {0.f, 0.f, 0.f, 0.f}, lB[4] = {0.f, 0.f, 0.f, 0.f};
    int irA[4], irB[4];
    #pragma unroll
    for (int q = 0; q < 4; ++q) {
        irA[q] = qt_lo * 64 + w * 16 + rbase + q;
        irB[q] = qt_hi * 64 + w * 16 + rbase + q;
    }

    for (int jt = 0; jt <= qt_hi; ++jt) {
        bool dolo = (jt <= qt_lo);

        // --- K/V fragments straight from global (XCD-local L2 hits)
        bf16x8 kfr[4][2], vfr[4][2];
        #pragma unroll
        for (int f = 0; f < 4; ++f) {
            const bf16* kp = Kbase + (long)(jt*64 + f*16 + row_l) * HD + ksl;
            kfr[f][0] = *(const bf16x8*)kp;
            kfr[f][1] = *(const bf16x8*)(kp + 32);
            const bf16* vp = Vbase + (long)(f*16 + row_l) * SEQ_ + jt*64 + ksl;
            vfr[f][0] = *(const bf16x8*)vp;
            vfr[f][1] = *(const bf16x8*)(vp + 32);
        }

        // --- S = Q K^T for both q-tiles
        f32x4 sA[4] = {}, sB[4] = {};
        __builtin_amdgcn_s_setprio(1);
        #pragma unroll
        for (int f = 0; f < 4; ++f) {
            sB[f] = __builtin_amdgcn_mfma_f32_16x16x32_bf16(qB0, kfr[f][0], sB[f], 0,0,0);
            sB[f] = __builtin_amdgcn_mfma_f32_16x16x32_bf16(qB1, kfr[f][1], sB[f], 0,0,0);
            if (dolo) {
                sA[f] = __builtin_amdgcn_mfma_f32_16x16x32_bf16(qA0, kfr[f][0], sA[f], 0,0,0);
                sA[f] = __builtin_amdgcn_mfma_f32_16x16x32_bf16(qA1, kfr[f][1], sA[f], 0,0,0);
            }
        }
        __builtin_amdgcn_s_setprio(0);

        {   // hi tile: P = exp(S+bias), l partials, PV
            #pragma unroll
            for (int f = 0; f < 4; ++f) {
                int j = jt * 64 + f * 16 + row_l;
                #pragma unroll
                for (int q = 0; q < 4; ++q) {
                    float sv = (j <= irB[q]) ? (sB[f][q] + biasS[irB[q] - j]) : -1e30f;
                    float p = __expf(sv);
                    lB[q] += p;
                    Ps[w][(rbase + q) * PSTRIDE + f * 16 + row_l] = (bf16)p;
                }
            }
            bf16x8 pf0 = *(const bf16x8*)&Ps[w][row_l * PSTRIDE + ksl];
            bf16x8 pf1 = *(const bf16x8*)&Ps[w][row_l * PSTRIDE + 32 + ksl];
            __builtin_amdgcn_s_setprio(1);
            #pragma unroll
            for (int db = 0; db < 4; ++db) {
                oaccB[db] = __builtin_amdgcn_mfma_f32_16x16x32_bf16(pf0, vfr[db][0], oaccB[db], 0,0,0);
                oaccB[db] = __builtin_amdgcn_mfma_f32_16x16x32_bf16(pf1, vfr[db][1], oaccB[db], 0,0,0);
            }
            __builtin_amdgcn_s_setprio(0);
        }

        if (dolo) {   // lo tile
            #pragma unroll
            for (int f = 0; f < 4; ++f) {
                int j = jt * 64 + f * 16 + row_l;
                #pragma unroll
                for (int q = 0; q < 4; ++q) {
                    float sv = (j <= irA[q]) ? (sA[f][q] + biasS[irA[q] - j]) : -1e30f;
                    float p = __expf(sv);
                    lA[q] += p;
                    Ps[w][(rbase + q) * PSTRIDE + f * 16 + row_l] = (bf16)p;
                }
            }
            bf16x8 pf0 = *(const bf16x8*)&Ps[w][row_l * PSTRIDE + ksl];
            bf16x8 pf1 = *(const bf16x8*)&Ps[w][row_l * PSTRIDE + 32 + ksl];
            __builtin_amdgcn_s_setprio(1);
            #pragma unroll
            for (int db = 0; db < 4; ++db) {
                oaccA[db] = __builtin_amdgcn_mfma_f32_16x16x32_bf16(pf0, vfr[db][0], oaccA[db], 0,0,0);
                oaccA[db] = __builtin_amdgcn_mfma_f32_16x16x32_bf16(pf1, vfr[db][1], oaccA[db], 0,0,0);
            }
            __builtin_amdgcn_s_setprio(0);
        }
    }

    // epilogue: reduce l across 16 lanes per q-row, write AO
    #pragma unroll
    for (int q = 0; q < 4; ++q) {
        float la = lA[q], lb = lB[q];
        #pragma unroll
        for (int off = 1; off < 16; off <<= 1) {
            la += __shfl_xor(la, off);
            lb += __shfl_xor(lb, off);
        }
        float invA = 1.0f / la;
        float invB = 1.0f / lb;
        long baseA = ((long)(b * SEQ_ + irA[q])) * DM + h * HD;
        long baseB = ((long)(b * SEQ_ + irB[q])) * DM + h * HD;
        #pragma unroll
        for (int db = 0; db < 4; ++db) {
            AO[baseA + db * 16 + row_l] = (bf16)(oaccA[db][q] * invA);
            AO[baseB + db * 16 + row_l] = (bf16)(oaccB[db][q] * invB);
        }
    }
}

// ---------------------------------------------------------------------------
extern "C" void kernel_launch(void* const* d_in, const int* in_sizes, int n_in,
                              void* d_out, int out_size, void* d_ws, size_t ws_size,
                              hipStream_t stream)
{
    const float* x   = (const float*)d_in[0];
    const float* Wq  = (const float*)d_in[1];
    const float* bq  = (const float*)d_in[2];
    const float* Wk  = (const float*)d_in[3];
    const float* bk  = (const float*)d_in[4];
    const float* Wv  = (const float*)d_in[5];
    const float* bv  = (const float*)d_in[6];
    const float* Wo  = (const float*)d_in[7];
    const float* bo  = (const float*)d_in[8];
    const float* rel = (const float*)d_in[9];
    float* out = (float*)d_out;

    char* ws = (char*)d_ws;
    bf16* xb    = (bf16*)ws;  ws += (size_t)B_*SEQ_*DM * 2;
    bf16* wqkvb = (bf16*)ws;  ws += (size_t)3*DM*DM * 2;
    bf16* wob   = (bf16*)ws;  ws += (size_t)DM*DM * 2;
    float* biasT= (float*)ws; ws += (size_t)H_*SEQ_ * 4;
    bf16* Qb    = (bf16*)ws;  ws += (size_t)B_*H_*SEQ_*HD * 2;
    bf16* Kb2   = (bf16*)ws;  ws += (size_t)B_*H_*SEQ_*HD * 2;
    bf16* Vtb   = (bf16*)ws;  ws += (size_t)B_*H_*SEQ_*HD * 2;
    bf16* AO    = (bf16*)ws;  ws += (size_t)B_*SEQ_*DM * 2;

    prep_kernel<<<2048, 256, 0, stream>>>(x, Wq, Wk, Wv, Wo, rel,
                                          xb, wqkvb, wob, biasT);

    // QKV: M=4096, N=3072 -> 32 x 24 = 768 blocks of 128x128
    gemm_ring<32><<<768, 256, 0, stream>>>(
        xb, wqkvb, Qb, Kb2, Vtb, bq, bk, bv);

    attn_kernel<<<512, 256, 0, stream>>>(Qb, Kb2, Vtb, biasT, AO);

    // out-proj: M=4096, N=1024 -> 32 x 16 = 512 blocks of 128x64
    gemm_ring_o<32><<<512, 256, 0, stream>>>(AO, wob, out, bo);
}

// Round 11
// 110.693 us; speedup vs baseline: 1.1392x; 1.1392x over previous
//
#include <hip/hip_runtime.h>
#include <hip/hip_bf16.h>
#include <stdint.h>

#define B_   4
#define SEQ_ 1024
#define DM   1024
#define H_   16
#define HD   64

typedef __bf16 bf16;
typedef __bf16 bf16x8 __attribute__((ext_vector_type(8)));
typedef __bf16 bf16x4v __attribute__((ext_vector_type(4)));
typedef __bf16 bf16x2 __attribute__((ext_vector_type(2)));
typedef float  f32x4 __attribute__((ext_vector_type(4)));

__device__ __forceinline__ void gl_lds16(const void* g, void* s_uniform) {
    __builtin_amdgcn_global_load_lds(
        (const __attribute__((address_space(1))) uint32_t*)g,
        (__attribute__((address_space(3))) uint32_t*)s_uniform,
        16, 0, 0);
}

// ---------------------------------------------------------------------------
// prep: fp32 -> bf16 casts + T5 relative-position bias table [h][dist]
// ---------------------------------------------------------------------------
__global__ __launch_bounds__(256) void prep_kernel(
    const float* __restrict__ x, const float* __restrict__ Wq,
    const float* __restrict__ Wk, const float* __restrict__ Wv,
    const float* __restrict__ Wo, const float* __restrict__ rel,
    bf16* __restrict__ xb, bf16* __restrict__ wqkvb, bf16* __restrict__ wob,
    float* __restrict__ biasT)
{
    int tid = blockIdx.x * 256 + threadIdx.x;
    int stride = gridDim.x * 256;

    for (int i = tid; i < (B_*SEQ_*DM)/4; i += stride) {
        float4 v = ((const float4*)x)[i];
        bf16x4v o; o[0]=(bf16)v.x; o[1]=(bf16)v.y; o[2]=(bf16)v.z; o[3]=(bf16)v.w;
        ((bf16x4v*)xb)[i] = o;
    }
    for (int i = tid; i < (3*DM*DM)/4; i += stride) {
        int n = i >> 8, k4 = i & 255;
        const float* src = (n < 1024) ? Wq : (n < 2048) ? Wk : Wv;
        float4 v = ((const float4*)(src + (size_t)(n & 1023) * DM))[k4];
        bf16x4v o; o[0]=(bf16)v.x; o[1]=(bf16)v.y; o[2]=(bf16)v.z; o[3]=(bf16)v.w;
        ((bf16x4v*)wqkvb)[i] = o;
    }
    for (int i = tid; i < (DM*DM)/4; i += stride) {
        float4 v = ((const float4*)Wo)[i];
        bf16x4v o; o[0]=(bf16)v.x; o[1]=(bf16)v.y; o[2]=(bf16)v.z; o[3]=(bf16)v.w;
        ((bf16x4v*)wob)[i] = o;
    }
    for (int i = tid; i < H_ * SEQ_; i += stride) {
        int h = i >> 10, dist = i & 1023;
        int bkt;
        if (dist < 16) {
            bkt = dist;
        } else {
            float r = logf((float)dist * (1.0f/16.0f)) / logf(8.0f) * 16.0f;
            int vb = 16 + (int)r;
            bkt = vb > 31 ? 31 : vb;
        }
        biasT[i] = rel[bkt * H_ + h] * 0.125f;
    }
}

// ---------------------------------------------------------------------------
// Ring GEMM (QKV): C = A @ B^T, BM=BN=128, BK=32, 256 thr (4 waves 2x2),
// 3 LDS buffers, depth-2 prefetch, counted vmcnt(4), chunk-XOR swizzle.
// Rectangle XCD swizzle. Q/K direct scatter; V via LDS transpose.
// ---------------------------------------------------------------------------
template<int NT>
__global__ __launch_bounds__(256, 3) void gemm_ring(
    const bf16* __restrict__ Ag, const bf16* __restrict__ Bg,
    bf16* __restrict__ qb, bf16* __restrict__ kb, bf16* __restrict__ vtb,
    const float* __restrict__ bq, const float* __restrict__ bk,
    const float* __restrict__ bv)
{
    __shared__ __align__(16) bf16 tile[3][256 * 32];   // 3 x 16 KB

    const int t = threadIdx.x;
    const int lane = t & 63, w = t >> 6;
    const int wr = w >> 1, wc = w & 1;
    const int row_l = lane & 15;
    const int lg = lane >> 4;

    int xcd = blockIdx.x & 7;
    int idx = blockIdx.x >> 3;
    int ty = (xcd >> 1) * 8 + idx / 12;
    int tx = (xcd & 1) * 12 + idx % 12;
    const int m0 = ty * 128, n0 = tx * 128;

    f32x4 acc[4][4] = {};

    auto STAGE = [&](int buf, int kt) {
        bf16* dst = &tile[buf][0];
        #pragma unroll
        for (int i = 0; i < 4; ++i) {
            int e = i * 2048 + t * 8;
            int r = e >> 5;
            int csw = ((t & 3) ^ (r & 3)) << 3;
            const bf16* src = (r < 128)
                ? (Ag + (long)(m0 + r) * 1024 + kt * 32 + csw)
                : (Bg + (long)(n0 + r - 128) * 1024 + kt * 32 + csw);
            gl_lds16(src, dst + i * 2048 + w * 512);
        }
    };

    auto COMPUTE = [&](int buf) {
        const bf16* bp = &tile[buf][0];
        bf16x8 af[4], bfr[4];
        #pragma unroll
        for (int m = 0; m < 4; ++m) {
            int ra = wr * 64 + m * 16 + row_l;
            af[m] = *(const bf16x8*)&bp[ra * 32 + ((lg ^ (ra & 3)) << 3)];
        }
        #pragma unroll
        for (int n = 0; n < 4; ++n) {
            int rb = 128 + wc * 64 + n * 16 + row_l;
            bfr[n] = *(const bf16x8*)&bp[rb * 32 + ((lg ^ (rb & 3)) << 3)];
        }
        #pragma unroll
        for (int m = 0; m < 4; ++m)
            #pragma unroll
            for (int n = 0; n < 4; ++n)
                acc[m][n] = __builtin_amdgcn_mfma_f32_16x16x32_bf16(
                    af[m], bfr[n], acc[m][n], 0, 0, 0);
    };

    STAGE(0, 0); STAGE(1, 1);
    asm volatile("s_waitcnt vmcnt(4)" ::: "memory");
    __builtin_amdgcn_s_barrier();

    int cb = 0;
    for (int kt = 0; kt < NT; ++kt) {
        int sb = cb - 1; if (sb < 0) sb += 3;
        if (kt + 2 < NT) STAGE(sb, kt + 2);
        COMPUTE(cb);
        if (kt + 2 < NT) { asm volatile("s_waitcnt vmcnt(4)" ::: "memory"); }
        else             { asm volatile("s_waitcnt vmcnt(0)" ::: "memory"); }
        __builtin_amdgcn_s_barrier();
        cb = (cb + 1 == 3) ? 0 : cb + 1;
    }

    const int rbase = (lane >> 4) * 4;

    if (n0 < 2048) {
        #pragma unroll
        for (int m = 0; m < 4; ++m) {
            #pragma unroll
            for (int n = 0; n < 4; ++n) {
                #pragma unroll
                for (int g = 0; g < 4; ++g) {
                    int gm = m0 + wr * 64 + m * 16 + rbase + g;
                    int gn = n0 + wc * 64 + n * 16 + row_l;
                    int which = gn >> 10, nn = gn & 1023;
                    int h = nn >> 6, d = nn & 63;
                    int b = gm >> 10, s = gm & 1023;
                    float v = acc[m][n][g] + ((which == 0) ? bq[nn] : bk[nn]);
                    bf16 bv16 = (bf16)v;
                    if (which == 0)
                        qb[((long)(b*H_ + h)*SEQ_ + s)*HD + d] = bv16;
                    else
                        kb[((long)(b*H_ + h)*SEQ_ + s)*HD + d] = bv16;
                }
            }
        }
    } else {
        // V epilogue: LDS transpose (XOR-staggered) -> coalesced Vt stores
        bf16* lt = &tile[0][0];
        #pragma unroll
        for (int m = 0; m < 4; ++m) {
            #pragma unroll
            for (int n = 0; n < 4; ++n) {
                int nl = wc * 64 + n * 16 + row_l;
                int mlb = wr * 64 + m * 16 + rbase;
                float bvv = bv[(n0 & 1023) + nl];
                #pragma unroll
                for (int g2 = 0; g2 < 2; ++g2) {
                    bf16x2 pk;
                    pk[0] = (bf16)(acc[m][n][2*g2]     + bvv);
                    pk[1] = (bf16)(acc[m][n][2*g2 + 1] + bvv);
                    int ml = mlb + 2 * g2;
                    int byte = nl * 256 + ((ml * 2) ^ ((nl & 15) << 4));
                    *(bf16x2*)((char*)lt + byte) = pk;
                }
            }
        }
        __syncthreads();
        {
            int nl = t >> 1, sc = t & 1;
            int nn = (n0 & 1023) + nl;
            int h = nn >> 6, d = nn & 63;
            int b = m0 >> 10, s0 = (m0 & 1023) + sc * 64;
            bf16* dst = vtb + ((long)(b*H_ + h)*HD + d)*SEQ_ + s0;
            #pragma unroll
            for (int i = 0; i < 8; ++i) {
                int byte = nl * 256 + ((sc * 128 + i * 16) ^ ((nl & 15) << 4));
                *(float4*)(dst + i * 8) = *(const float4*)((char*)lt + byte);
            }
        }
    }
}

// ---------------------------------------------------------------------------
// Ring GEMM (out-proj): BM=128, BN=64, BK=32, 3 bufs, counted vmcnt.
// ---------------------------------------------------------------------------
template<int NT>
__global__ __launch_bounds__(256, 2) void gemm_ring_o(
    const bf16* __restrict__ Ag, const bf16* __restrict__ Bg,
    float* __restrict__ outp, const float* __restrict__ bo)
{
    __shared__ __align__(16) bf16 tile[3][192 * 32];

    const int t = threadIdx.x;
    const int lane = t & 63, w = t >> 6;
    const int wr = w >> 1, wc = w & 1;
    const int row_l = lane & 15;
    const int lg = lane >> 4;

    int xcd = blockIdx.x & 7;
    int idx = blockIdx.x >> 3;
    int ty = (xcd >> 1) * 8 + (idx >> 3);
    int tx = (xcd & 1) * 8 + (idx & 7);
    const int m0 = ty * 128, n0 = tx * 64;

    f32x4 acc[4][2] = {};

    auto STAGE = [&](int buf, int kt) {
        bf16* dst = &tile[buf][0];
        #pragma unroll
        for (int i = 0; i < 3; ++i) {
            int e = i * 2048 + t * 8;
            int r = e >> 5;
            int csw = ((t & 3) ^ (r & 3)) << 3;
            const bf16* src = (r < 128)
                ? (Ag + (long)(m0 + r) * 1024 + kt * 32 + csw)
                : (Bg + (long)(n0 + r - 128) * 1024 + kt * 32 + csw);
            gl_lds16(src, dst + i * 2048 + w * 512);
        }
    };

    auto COMPUTE = [&](int buf) {
        const bf16* bp = &tile[buf][0];
        bf16x8 af[4], bfr[2];
        #pragma unroll
        for (int m = 0; m < 4; ++m) {
            int ra = wr * 64 + m * 16 + row_l;
            af[m] = *(const bf16x8*)&bp[ra * 32 + ((lg ^ (ra & 3)) << 3)];
        }
        #pragma unroll
        for (int n = 0; n < 2; ++n) {
            int rb = 128 + wc * 32 + n * 16 + row_l;
            bfr[n] = *(const bf16x8*)&bp[rb * 32 + ((lg ^ (rb & 3)) << 3)];
        }
        #pragma unroll
        for (int m = 0; m < 4; ++m)
            #pragma unroll
            for (int n = 0; n < 2; ++n)
                acc[m][n] = __builtin_amdgcn_mfma_f32_16x16x32_bf16(
                    af[m], bfr[n], acc[m][n], 0, 0, 0);
    };

    STAGE(0, 0); STAGE(1, 1);
    asm volatile("s_waitcnt vmcnt(3)" ::: "memory");
    __builtin_amdgcn_s_barrier();

    int cb = 0;
    for (int kt = 0; kt < NT; ++kt) {
        int sb = cb - 1; if (sb < 0) sb += 3;
        if (kt + 2 < NT) STAGE(sb, kt + 2);
        COMPUTE(cb);
        if (kt + 2 < NT) { asm volatile("s_waitcnt vmcnt(3)" ::: "memory"); }
        else             { asm volatile("s_waitcnt vmcnt(0)" ::: "memory"); }
        __builtin_amdgcn_s_barrier();
        cb = (cb + 1 == 3) ? 0 : cb + 1;
    }

    const int rbase = (lane >> 4) * 4;
    #pragma unroll
    for (int m = 0; m < 4; ++m) {
        #pragma unroll
        for (int n = 0; n < 2; ++n) {
            #pragma unroll
            for (int g = 0; g < 4; ++g) {
                int gm = m0 + wr * 64 + m * 16 + rbase + g;
                int gn = n0 + wc * 32 + n * 16 + row_l;
                outp[(long)gm * DM + gn] = acc[m][n][g] + bo[gn];
            }
        }
    }
}

// ---------------------------------------------------------------------------
// Flash attention v6: q-split, grid 1024 (one 64-row q-tile per block),
// 4 blocks/CU (16 waves/CU). CU-balanced qt assignment (columns sum to 34
// steps). K LDS double-buffered via gl_lds (one barrier/step); V direct
// global->reg issued early, consumed after exp (latency hidden under
// QK^T+exp). Static-shift softmax. XCD-local groups.
// ---------------------------------------------------------------------------
#define PSTRIDE 72

__global__ __launch_bounds__(256, 4) void attn_kernel(
    const bf16* __restrict__ Qb, const bf16* __restrict__ Kb,
    const bf16* __restrict__ Vtb, const float* __restrict__ biasT,
    bf16* __restrict__ AO)
{
    __shared__ __align__(16) bf16 Ks[2][64 * 64];      // 16 KB
    __shared__ __align__(16) bf16 Ps[4][16 * PSTRIDE]; // 9 KB
    __shared__ float biasS[SEQ_];                      // 4 KB

    int t = threadIdx.x;
    int lane = t & 63, w = t >> 6;

    // decode: xcd-local group; CU-balanced qt (blocks on one CU sum to 34)
    int bid = blockIdx.x;
    int xcd = bid & 7;
    int widx = bid >> 3;            // 0..127
    int rnd = widx >> 5;            // 0..3
    int lo  = widx & 31;
    int g = xcd * 8 + (lo >> 2);    // bh group
    int a = lo & 3;
    int qt = (rnd == 0) ? a : (rnd == 1) ? 15 - a : (rnd == 2) ? 7 - a : 8 + a;
    int h = g & 15, b = g >> 4;

    int row_l = lane & 15;
    int ksl = (lane >> 4) * 8;
    int rbase = (lane >> 4) * 4;

    ((float4*)biasS)[t] = ((const float4*)(biasT + (long)h * SEQ_))[t];

    const bf16* Kbase = Kb + (long)g * SEQ_ * HD;
    const bf16* Vbase = Vtb + (long)g * HD * SEQ_;

    const bf16* Qp = Qb + ((long)g * SEQ_ + qt * 64 + w * 16) * HD;
    bf16x8 qf0 = *(const bf16x8*)&Qp[row_l * HD + ksl];
    bf16x8 qf1 = *(const bf16x8*)&Qp[row_l * HD + 32 + ksl];

    f32x4 oacc[4] = {};
    float lsum[4] = {0.f, 0.f, 0.f, 0.f};
    int ir[4];
    #pragma unroll
    for (int q = 0; q < 4; ++q) ir[q] = qt * 64 + w * 16 + rbase + q;

    // K tile jt -> Ks[jt&1]; pre-swizzled source, linear LDS dest
    auto stageK = [&](int jt) {
        bf16* dst = &Ks[jt & 1][0];
        #pragma unroll
        for (int i = 0; i < 2; ++i) {
            int e = i * 2048 + t * 8;
            int r = e >> 6;                              // 0..63
            int csw = ((((e >> 3) & 7) ^ (r & 7)) << 3); // inverse-swz col
            gl_lds16(Kbase + (long)(jt * 64 + r) * HD + csw,
                     dst + i * 2048 + w * 512);
        }
    };

    stageK(0);

    for (int jt = 0; jt <= qt; ++jt) {
        // stage(jt) complete (own loads), then block-wide join:
        // prev-step K reads drained + K(jt) visible to all waves
        asm volatile("s_waitcnt vmcnt(0)" ::: "memory");
        __builtin_amdgcn_s_barrier();

        if (jt < qt) stageK(jt + 1);

        // V(jt) direct to regs, issued early (consumed after exp)
        bf16x8 vfr[4][2];
        #pragma unroll
        for (int f = 0; f < 4; ++f) {
            const bf16* vp = Vbase + (long)(f * 16 + row_l) * SEQ_ + jt * 64 + ksl;
            vfr[f][0] = *(const bf16x8*)vp;
            vfr[f][1] = *(const bf16x8*)(vp + 32);
        }

        // QK^T from LDS (swizzled reads)
        f32x4 s[4] = {};
        __builtin_amdgcn_s_setprio(1);
        #pragma unroll
        for (int f = 0; f < 4; ++f) {
            int ra = f * 16 + row_l;
            int a0 = (ra * 64 + ksl)      ^ ((ra & 7) << 3);
            int a1 = (ra * 64 + 32 + ksl) ^ ((ra & 7) << 3);
            bf16x8 kf0 = *(const bf16x8*)&Ks[jt & 1][a0];
            bf16x8 kf1 = *(const bf16x8*)&Ks[jt & 1][a1];
            s[f] = __builtin_amdgcn_mfma_f32_16x16x32_bf16(qf0, kf0, s[f], 0,0,0);
            s[f] = __builtin_amdgcn_mfma_f32_16x16x32_bf16(qf1, kf1, s[f], 0,0,0);
        }
        __builtin_amdgcn_s_setprio(0);

        // static-shift softmax: P = exp(S + bias); per-lane l partials
        #pragma unroll
        for (int f = 0; f < 4; ++f) {
            int j = jt * 64 + f * 16 + row_l;
            #pragma unroll
            for (int q = 0; q < 4; ++q) {
                float sv = (j <= ir[q]) ? (s[f][q] + biasS[ir[q] - j]) : -1e30f;
                float p = __expf(sv);
                lsum[q] += p;
                Ps[w][(rbase + q) * PSTRIDE + f * 16 + row_l] = (bf16)p;
            }
        }
        bf16x8 pf0 = *(const bf16x8*)&Ps[w][row_l * PSTRIDE + ksl];
        bf16x8 pf1 = *(const bf16x8*)&Ps[w][row_l * PSTRIDE + 32 + ksl];

        // PV (compiler waits vfr's own vmem counts)
        __builtin_amdgcn_s_setprio(1);
        #pragma unroll
        for (int db = 0; db < 4; ++db) {
            oacc[db] = __builtin_amdgcn_mfma_f32_16x16x32_bf16(pf0, vfr[db][0], oacc[db], 0,0,0);
            oacc[db] = __builtin_amdgcn_mfma_f32_16x16x32_bf16(pf1, vfr[db][1], oacc[db], 0,0,0);
        }
        __builtin_amdgcn_s_setprio(0);
    }

    // epilogue: row-sum reduce across the 16 k-col lanes, write AO
    #pragma unroll
    for (int q = 0; q < 4; ++q) {
        float l = lsum[q];
        #pragma unroll
        for (int off = 1; off < 16; off <<= 1) l += __shfl_xor(l, off);
        float inv = 1.0f / l;
        long base = ((long)(b * SEQ_ + ir[q])) * DM + h * HD;
        #pragma unroll
        for (int db = 0; db < 4; ++db)
            AO[base + db * 16 + row_l] = (bf16)(oacc[db][q] * inv);
    }
}

// ---------------------------------------------------------------------------
extern "C" void kernel_launch(void* const* d_in, const int* in_sizes, int n_in,
                              void* d_out, int out_size, void* d_ws, size_t ws_size,
                              hipStream_t stream)
{
    const float* x   = (const float*)d_in[0];
    const float* Wq  = (const float*)d_in[1];
    const float* bq  = (const float*)d_in[2];
    const float* Wk  = (const float*)d_in[3];
    const float* bk  = (const float*)d_in[4];
    const float* Wv  = (const float*)d_in[5];
    const float* bv  = (const float*)d_in[6];
    const float* Wo  = (const float*)d_in[7];
    const float* bo  = (const float*)d_in[8];
    const float* rel = (const float*)d_in[9];
    float* out = (float*)d_out;

    char* ws = (char*)d_ws;
    bf16* xb    = (bf16*)ws;  ws += (size_t)B_*SEQ_*DM * 2;
    bf16* wqkvb = (bf16*)ws;  ws += (size_t)3*DM*DM * 2;
    bf16* wob   = (bf16*)ws;  ws += (size_t)DM*DM * 2;
    float* biasT= (float*)ws; ws += (size_t)H_*SEQ_ * 4;
    bf16* Qb    = (bf16*)ws;  ws += (size_t)B_*H_*SEQ_*HD * 2;
    bf16* Kb2   = (bf16*)ws;  ws += (size_t)B_*H_*SEQ_*HD * 2;
    bf16* Vtb   = (bf16*)ws;  ws += (size_t)B_*H_*SEQ_*HD * 2;
    bf16* AO    = (bf16*)ws;  ws += (size_t)B_*SEQ_*DM * 2;

    prep_kernel<<<2048, 256, 0, stream>>>(x, Wq, Wk, Wv, Wo, rel,
                                          xb, wqkvb, wob, biasT);

    // QKV: M=4096, N=3072 -> 32 x 24 = 768 blocks of 128x128
    gemm_ring<32><<<768, 256, 0, stream>>>(
        xb, wqkvb, Qb, Kb2, Vtb, bq, bk, bv);

    attn_kernel<<<1024, 256, 0, stream>>>(Qb, Kb2, Vtb, biasT, AO);

    // out-proj: M=4096, N=1024 -> 32 x 16 = 512 blocks of 128x64
    gemm_ring_o<32><<<512, 256, 0, stream>>>(AO, wob, out, bo);
}

// Round 12
// 98.832 us; speedup vs baseline: 1.2759x; 1.1200x over previous
//
#include <hip/hip_runtime.h>
#include <hip/hip_bf16.h>
#include <stdint.h>

#define B_   4
#define SEQ_ 1024
#define DM   1024
#define H_   16
#define HD   64

typedef __bf16 bf16;
typedef __bf16 bf16x8 __attribute__((ext_vector_type(8)));
typedef __bf16 bf16x4v __attribute__((ext_vector_type(4)));
typedef __bf16 bf16x2 __attribute__((ext_vector_type(2)));
typedef float  f32x4 __attribute__((ext_vector_type(4)));

__device__ __forceinline__ void gl_lds16(const void* g, void* s_uniform) {
    __builtin_amdgcn_global_load_lds(
        (const __attribute__((address_space(1))) uint32_t*)g,
        (__attribute__((address_space(3))) uint32_t*)s_uniform,
        16, 0, 0);
}

// ---------------------------------------------------------------------------
// prep: fp32 -> bf16 casts + T5 bias table [h][dist] (pre-scaled by log2e)
// ---------------------------------------------------------------------------
__global__ __launch_bounds__(256) void prep_kernel(
    const float* __restrict__ x, const float* __restrict__ Wq,
    const float* __restrict__ Wk, const float* __restrict__ Wv,
    const float* __restrict__ Wo, const float* __restrict__ rel,
    bf16* __restrict__ xb, bf16* __restrict__ wqkvb, bf16* __restrict__ wob,
    float* __restrict__ biasT)
{
    int tid = blockIdx.x * 256 + threadIdx.x;
    int stride = gridDim.x * 256;

    for (int i = tid; i < (B_*SEQ_*DM)/4; i += stride) {
        float4 v = ((const float4*)x)[i];
        bf16x4v o; o[0]=(bf16)v.x; o[1]=(bf16)v.y; o[2]=(bf16)v.z; o[3]=(bf16)v.w;
        ((bf16x4v*)xb)[i] = o;
    }
    for (int i = tid; i < (3*DM*DM)/4; i += stride) {
        int n = i >> 8, k4 = i & 255;
        const float* src = (n < 1024) ? Wq : (n < 2048) ? Wk : Wv;
        float4 v = ((const float4*)(src + (size_t)(n & 1023) * DM))[k4];
        bf16x4v o; o[0]=(bf16)v.x; o[1]=(bf16)v.y; o[2]=(bf16)v.z; o[3]=(bf16)v.w;
        ((bf16x4v*)wqkvb)[i] = o;
    }
    for (int i = tid; i < (DM*DM)/4; i += stride) {
        float4 v = ((const float4*)Wo)[i];
        bf16x4v o; o[0]=(bf16)v.x; o[1]=(bf16)v.y; o[2]=(bf16)v.z; o[3]=(bf16)v.w;
        ((bf16x4v*)wob)[i] = o;
    }
    for (int i = tid; i < H_ * SEQ_; i += stride) {
        int h = i >> 10, dist = i & 1023;
        int bkt;
        if (dist < 16) {
            bkt = dist;
        } else {
            float r = logf((float)dist * (1.0f/16.0f)) / logf(8.0f) * 16.0f;
            int vb = 16 + (int)r;
            bkt = vb > 31 ? 31 : vb;
        }
        // 0.125 (head-dim scale) * log2(e)  -> attn uses exp2
        biasT[i] = rel[bkt * H_ + h] * (0.125f * 1.4426950408889634f);
    }
}

// ---------------------------------------------------------------------------
// Ring GEMM (QKV): C = A @ B^T, BM=BN=128, BK=32, 256 thr (4 waves 2x2),
// 3 LDS buffers, depth-2 prefetch, counted vmcnt(4), chunk-XOR swizzle.
// Rectangle XCD swizzle. Q scaled by log2e (exp2 folding); Q/K direct
// scatter; V via LDS transpose -> coalesced Vt stores.
// ---------------------------------------------------------------------------
template<int NT>
__global__ __launch_bounds__(256, 3) void gemm_ring(
    const bf16* __restrict__ Ag, const bf16* __restrict__ Bg,
    bf16* __restrict__ qb, bf16* __restrict__ kb, bf16* __restrict__ vtb,
    const float* __restrict__ bq, const float* __restrict__ bk,
    const float* __restrict__ bv)
{
    __shared__ __align__(16) bf16 tile[3][256 * 32];   // 3 x 16 KB

    const int t = threadIdx.x;
    const int lane = t & 63, w = t >> 6;
    const int wr = w >> 1, wc = w & 1;
    const int row_l = lane & 15;
    const int lg = lane >> 4;

    int xcd = blockIdx.x & 7;
    int idx = blockIdx.x >> 3;
    int ty = (xcd >> 1) * 8 + idx / 12;
    int tx = (xcd & 1) * 12 + idx % 12;
    const int m0 = ty * 128, n0 = tx * 128;

    f32x4 acc[4][4] = {};

    auto STAGE = [&](int buf, int kt) {
        bf16* dst = &tile[buf][0];
        #pragma unroll
        for (int i = 0; i < 4; ++i) {
            int e = i * 2048 + t * 8;
            int r = e >> 5;
            int csw = ((t & 3) ^ (r & 3)) << 3;
            const bf16* src = (r < 128)
                ? (Ag + (long)(m0 + r) * 1024 + kt * 32 + csw)
                : (Bg + (long)(n0 + r - 128) * 1024 + kt * 32 + csw);
            gl_lds16(src, dst + i * 2048 + w * 512);
        }
    };

    auto COMPUTE = [&](int buf) {
        const bf16* bp = &tile[buf][0];
        bf16x8 af[4], bfr[4];
        #pragma unroll
        for (int m = 0; m < 4; ++m) {
            int ra = wr * 64 + m * 16 + row_l;
            af[m] = *(const bf16x8*)&bp[ra * 32 + ((lg ^ (ra & 3)) << 3)];
        }
        #pragma unroll
        for (int n = 0; n < 4; ++n) {
            int rb = 128 + wc * 64 + n * 16 + row_l;
            bfr[n] = *(const bf16x8*)&bp[rb * 32 + ((lg ^ (rb & 3)) << 3)];
        }
        #pragma unroll
        for (int m = 0; m < 4; ++m)
            #pragma unroll
            for (int n = 0; n < 4; ++n)
                acc[m][n] = __builtin_amdgcn_mfma_f32_16x16x32_bf16(
                    af[m], bfr[n], acc[m][n], 0, 0, 0);
    };

    STAGE(0, 0); STAGE(1, 1);
    asm volatile("s_waitcnt vmcnt(4)" ::: "memory");
    __builtin_amdgcn_s_barrier();

    int cb = 0;
    for (int kt = 0; kt < NT; ++kt) {
        int sb = cb - 1; if (sb < 0) sb += 3;
        if (kt + 2 < NT) STAGE(sb, kt + 2);
        COMPUTE(cb);
        if (kt + 2 < NT) { asm volatile("s_waitcnt vmcnt(4)" ::: "memory"); }
        else             { asm volatile("s_waitcnt vmcnt(0)" ::: "memory"); }
        __builtin_amdgcn_s_barrier();
        cb = (cb + 1 == 3) ? 0 : cb + 1;
    }

    const int rbase = (lane >> 4) * 4;

    if (n0 < 2048) {
        #pragma unroll
        for (int m = 0; m < 4; ++m) {
            #pragma unroll
            for (int n = 0; n < 4; ++n) {
                #pragma unroll
                for (int g = 0; g < 4; ++g) {
                    int gm = m0 + wr * 64 + m * 16 + rbase + g;
                    int gn = n0 + wc * 64 + n * 16 + row_l;
                    int which = gn >> 10, nn = gn & 1023;
                    int h = nn >> 6, d = nn & 63;
                    int b = gm >> 10, s = gm & 1023;
                    float v = acc[m][n][g] + ((which == 0) ? bq[nn] : bk[nn]);
                    if (which == 0) v *= 1.4426950408889634f;  // exp2 folding
                    bf16 bv16 = (bf16)v;
                    if (which == 0)
                        qb[((long)(b*H_ + h)*SEQ_ + s)*HD + d] = bv16;
                    else
                        kb[((long)(b*H_ + h)*SEQ_ + s)*HD + d] = bv16;
                }
            }
        }
    } else {
        // V epilogue: LDS transpose (XOR-staggered) -> coalesced Vt stores
        bf16* lt = &tile[0][0];
        #pragma unroll
        for (int m = 0; m < 4; ++m) {
            #pragma unroll
            for (int n = 0; n < 4; ++n) {
                int nl = wc * 64 + n * 16 + row_l;
                int mlb = wr * 64 + m * 16 + rbase;
                float bvv = bv[(n0 & 1023) + nl];
                #pragma unroll
                for (int g2 = 0; g2 < 2; ++g2) {
                    bf16x2 pk;
                    pk[0] = (bf16)(acc[m][n][2*g2]     + bvv);
                    pk[1] = (bf16)(acc[m][n][2*g2 + 1] + bvv);
                    int ml = mlb + 2 * g2;
                    int byte = nl * 256 + ((ml * 2) ^ ((nl & 15) << 4));
                    *(bf16x2*)((char*)lt + byte) = pk;
                }
            }
        }
        __syncthreads();
        {
            int nl = t >> 1, sc = t & 1;
            int nn = (n0 & 1023) + nl;
            int h = nn >> 6, d = nn & 63;
            int b = m0 >> 10, s0 = (m0 & 1023) + sc * 64;
            bf16* dst = vtb + ((long)(b*H_ + h)*HD + d)*SEQ_ + s0;
            #pragma unroll
            for (int i = 0; i < 8; ++i) {
                int byte = nl * 256 + ((sc * 128 + i * 16) ^ ((nl & 15) << 4));
                *(float4*)(dst + i * 8) = *(const float4*)((char*)lt + byte);
            }
        }
    }
}

// ---------------------------------------------------------------------------
// Ring GEMM (out-proj): BM=128, BN=64, BK=32, 3 bufs, counted vmcnt.
// ---------------------------------------------------------------------------
template<int NT>
__global__ __launch_bounds__(256, 2) void gemm_ring_o(
    const bf16* __restrict__ Ag, const bf16* __restrict__ Bg,
    float* __restrict__ outp, const float* __restrict__ bo)
{
    __shared__ __align__(16) bf16 tile[3][192 * 32];

    const int t = threadIdx.x;
    const int lane = t & 63, w = t >> 6;
    const int wr = w >> 1, wc = w & 1;
    const int row_l = lane & 15;
    const int lg = lane >> 4;

    int xcd = blockIdx.x & 7;
    int idx = blockIdx.x >> 3;
    int ty = (xcd >> 1) * 8 + (idx >> 3);
    int tx = (xcd & 1) * 8 + (idx & 7);
    const int m0 = ty * 128, n0 = tx * 64;

    f32x4 acc[4][2] = {};

    auto STAGE = [&](int buf, int kt) {
        bf16* dst = &tile[buf][0];
        #pragma unroll
        for (int i = 0; i < 3; ++i) {
            int e = i * 2048 + t * 8;
            int r = e >> 5;
            int csw = ((t & 3) ^ (r & 3)) << 3;
            const bf16* src = (r < 128)
                ? (Ag + (long)(m0 + r) * 1024 + kt * 32 + csw)
                : (Bg + (long)(n0 + r - 128) * 1024 + kt * 32 + csw);
            gl_lds16(src, dst + i * 2048 + w * 512);
        }
    };

    auto COMPUTE = [&](int buf) {
        const bf16* bp = &tile[buf][0];
        bf16x8 af[4], bfr[2];
        #pragma unroll
        for (int m = 0; m < 4; ++m) {
            int ra = wr * 64 + m * 16 + row_l;
            af[m] = *(const bf16x8*)&bp[ra * 32 + ((lg ^ (ra & 3)) << 3)];
        }
        #pragma unroll
        for (int n = 0; n < 2; ++n) {
            int rb = 128 + wc * 32 + n * 16 + row_l;
            bfr[n] = *(const bf16x8*)&bp[rb * 32 + ((lg ^ (rb & 3)) << 3)];
        }
        #pragma unroll
        for (int m = 0; m < 4; ++m)
            #pragma unroll
            for (int n = 0; n < 2; ++n)
                acc[m][n] = __builtin_amdgcn_mfma_f32_16x16x32_bf16(
                    af[m], bfr[n], acc[m][n], 0, 0, 0);
    };

    STAGE(0, 0); STAGE(1, 1);
    asm volatile("s_waitcnt vmcnt(3)" ::: "memory");
    __builtin_amdgcn_s_barrier();

    int cb = 0;
    for (int kt = 0; kt < NT; ++kt) {
        int sb = cb - 1; if (sb < 0) sb += 3;
        if (kt + 2 < NT) STAGE(sb, kt + 2);
        COMPUTE(cb);
        if (kt + 2 < NT) { asm volatile("s_waitcnt vmcnt(3)" ::: "memory"); }
        else             { asm volatile("s_waitcnt vmcnt(0)" ::: "memory"); }
        __builtin_amdgcn_s_barrier();
        cb = (cb + 1 == 3) ? 0 : cb + 1;
    }

    const int rbase = (lane >> 4) * 4;
    #pragma unroll
    for (int m = 0; m < 4; ++m) {
        #pragma unroll
        for (int n = 0; n < 2; ++n) {
            #pragma unroll
            for (int g = 0; g < 4; ++g) {
                int gm = m0 + wr * 64 + m * 16 + rbase + g;
                int gn = n0 + wc * 32 + n * 16 + row_l;
                outp[(long)gm * DM + gn] = acc[m][n][g] + bo[gn];
            }
        }
    }
}

// ---------------------------------------------------------------------------
// Flash attention v7: R9 structure with 512-thread blocks (16 waves/CU).
// Block = one group, one causal pair {p, 15-p}. Waves 0-3: lo tile frags,
// waves 4-7: hi tile frags (16 rows each). K+V double-buffered LDS staged
// by all 512 threads (2 gl_lds/thread/step); one drain+barrier per step.
// Static-shift softmax with exp2 (Q and bias pre-scaled by log2e).
// ---------------------------------------------------------------------------
#define PSTRIDE 72

__global__ __launch_bounds__(512, 4) void attn_kernel(
    const bf16* __restrict__ Qb, const bf16* __restrict__ Kb,
    const bf16* __restrict__ Vtb, const float* __restrict__ biasT,
    bf16* __restrict__ AO)
{
    __shared__ __align__(16) bf16 Ks[2][64 * 64];        // 16 KB
    __shared__ __align__(16) bf16 Vs[2][64 * 64];        // 16 KB
    __shared__ __align__(16) bf16 Ps[8][16 * PSTRIDE];   // 18 KB
    __shared__ float biasS[SEQ_];                        // 4 KB

    int t = threadIdx.x;
    int lane = t & 63, w = t >> 6;

    // decode: XCD-local groups (8/XCD); p = causal pair index
    int bid = blockIdx.x;
    int xcd = bid & 7;
    int rest = bid >> 3;            // 0..63
    int g = xcd * 8 + (rest & 7);
    int p = rest >> 3;              // 0..7
    int qt_hi = 15 - p;
    int h = g & 15, b = g >> 4;

    // wave -> tile assignment
    int qtw = (w < 4) ? p : qt_hi;          // this wave's q-tile
    int row0 = qtw * 64 + (w & 3) * 16;     // wave's 16 q-rows

    int row_l = lane & 15;
    int ksl = (lane >> 4) * 8;
    int rbase = (lane >> 4) * 4;

    const bf16* Kbase = Kb + (long)g * SEQ_ * HD;
    const bf16* Vbase = Vtb + (long)g * HD * SEQ_;

    // stage K+V tile jt (512 threads, 1 gl_lds each for K and V)
    auto stageKV = [&](int jt) {
        int e = t * 8;
        int r = e >> 6;                                  // 0..63
        int csw = ((((e >> 3) & 7) ^ (r & 7)) << 3);     // inverse-swz col
        gl_lds16(Kbase + (long)(jt * 64 + r) * HD + csw, &Ks[jt & 1][0] + w * 512);
        gl_lds16(Vbase + (long)r * SEQ_ + jt * 64 + csw, &Vs[jt & 1][0] + w * 512);
    };

    stageKV(0);
    if (t < 256)
        ((float4*)biasS)[t] = ((const float4*)(biasT + (long)h * SEQ_))[t];

    // Q fragment (16 rows) for this wave
    const bf16* Qp = Qb + ((long)g * SEQ_ + row0) * HD;
    bf16x8 qf0 = *(const bf16x8*)&Qp[row_l * HD + ksl];
    bf16x8 qf1 = *(const bf16x8*)&Qp[row_l * HD + 32 + ksl];

    f32x4 oacc[4] = {};
    float lsum[4] = {0.f, 0.f, 0.f, 0.f};
    int ir[4];
    #pragma unroll
    for (int q = 0; q < 4; ++q) ir[q] = row0 + rbase + q;

    for (int jt = 0; jt <= qt_hi; ++jt) {
        asm volatile("s_waitcnt vmcnt(0)" ::: "memory");
        __builtin_amdgcn_s_barrier();
        if (jt < qt_hi) stageKV(jt + 1);

        if (jt <= qtw) {
            const bf16* kb_ = &Ks[jt & 1][0];
            const bf16* vb_ = &Vs[jt & 1][0];

            // QK^T
            f32x4 s[4] = {};
            __builtin_amdgcn_s_setprio(1);
            #pragma unroll
            for (int f = 0; f < 4; ++f) {
                int ra = f * 16 + row_l;
                int a0 = (ra * 64 + ksl)      ^ ((ra & 7) << 3);
                int a1 = (ra * 64 + 32 + ksl) ^ ((ra & 7) << 3);
                bf16x8 kf0 = *(const bf16x8*)&kb_[a0];
                bf16x8 kf1 = *(const bf16x8*)&kb_[a1];
                s[f] = __builtin_amdgcn_mfma_f32_16x16x32_bf16(qf0, kf0, s[f], 0,0,0);
                s[f] = __builtin_amdgcn_mfma_f32_16x16x32_bf16(qf1, kf1, s[f], 0,0,0);
            }
            __builtin_amdgcn_s_setprio(0);

            // static-shift softmax: P = exp2(S' + bias'); per-lane l partials
            #pragma unroll
            for (int f = 0; f < 4; ++f) {
                int j = jt * 64 + f * 16 + row_l;
                #pragma unroll
                for (int q = 0; q < 4; ++q) {
                    float sv = (j <= ir[q]) ? (s[f][q] + biasS[ir[q] - j]) : -1e30f;
                    float pexp = exp2f(sv);
                    lsum[q] += pexp;
                    Ps[w][(rbase + q) * PSTRIDE + f * 16 + row_l] = (bf16)pexp;
                }
            }
            bf16x8 pf0 = *(const bf16x8*)&Ps[w][row_l * PSTRIDE + ksl];
            bf16x8 pf1 = *(const bf16x8*)&Ps[w][row_l * PSTRIDE + 32 + ksl];

            // PV
            __builtin_amdgcn_s_setprio(1);
            #pragma unroll
            for (int db = 0; db < 4; ++db) {
                int ra = db * 16 + row_l;
                int a0 = (ra * 64 + ksl)      ^ ((ra & 7) << 3);
                int a1 = (ra * 64 + 32 + ksl) ^ ((ra & 7) << 3);
                bf16x8 vf0 = *(const bf16x8*)&vb_[a0];
                bf16x8 vf1 = *(const bf16x8*)&vb_[a1];
                oacc[db] = __builtin_amdgcn_mfma_f32_16x16x32_bf16(pf0, vf0, oacc[db], 0,0,0);
                oacc[db] = __builtin_amdgcn_mfma_f32_16x16x32_bf16(pf1, vf1, oacc[db], 0,0,0);
            }
            __builtin_amdgcn_s_setprio(0);
        }
    }

    // epilogue: row-sum reduce across the 16 k-col lanes, write AO
    #pragma unroll
    for (int q = 0; q < 4; ++q) {
        float l = lsum[q];
        #pragma unroll
        for (int off = 1; off < 16; off <<= 1) l += __shfl_xor(l, off);
        float inv = 1.0f / l;
        long base = ((long)(b * SEQ_ + ir[q])) * DM + h * HD;
        #pragma unroll
        for (int db = 0; db < 4; ++db)
            AO[base + db * 16 + row_l] = (bf16)(oacc[db][q] * inv);
    }
}

// ---------------------------------------------------------------------------
extern "C" void kernel_launch(void* const* d_in, const int* in_sizes, int n_in,
                              void* d_out, int out_size, void* d_ws, size_t ws_size,
                              hipStream_t stream)
{
    const float* x   = (const float*)d_in[0];
    const float* Wq  = (const float*)d_in[1];
    const float* bq  = (const float*)d_in[2];
    const float* Wk  = (const float*)d_in[3];
    const float* bk  = (const float*)d_in[4];
    const float* Wv  = (const float*)d_in[5];
    const float* bv  = (const float*)d_in[6];
    const float* Wo  = (const float*)d_in[7];
    const float* bo  = (const float*)d_in[8];
    const float* rel = (const float*)d_in[9];
    float* out = (float*)d_out;

    char* ws = (char*)d_ws;
    bf16* xb    = (bf16*)ws;  ws += (size_t)B_*SEQ_*DM * 2;
    bf16* wqkvb = (bf16*)ws;  ws += (size_t)3*DM*DM * 2;
    bf16* wob   = (bf16*)ws;  ws += (size_t)DM*DM * 2;
    float* biasT= (float*)ws; ws += (size_t)H_*SEQ_ * 4;
    bf16* Qb    = (bf16*)ws;  ws += (size_t)B_*H_*SEQ_*HD * 2;
    bf16* Kb2   = (bf16*)ws;  ws += (size_t)B_*H_*SEQ_*HD * 2;
    bf16* Vtb   = (bf16*)ws;  ws += (size_t)B_*H_*SEQ_*HD * 2;
    bf16* AO    = (bf16*)ws;  ws += (size_t)B_*SEQ_*DM * 2;

    prep_kernel<<<2048, 256, 0, stream>>>(x, Wq, Wk, Wv, Wo, rel,
                                          xb, wqkvb, wob, biasT);

    // QKV: M=4096, N=3072 -> 32 x 24 = 768 blocks of 128x128
    gemm_ring<32><<<768, 256, 0, stream>>>(
        xb, wqkvb, Qb, Kb2, Vtb, bq, bk, bv);

    attn_kernel<<<512, 512, 0, stream>>>(Qb, Kb2, Vtb, biasT, AO);

    // out-proj: M=4096, N=1024 -> 32 x 16 = 512 blocks of 128x64
    gemm_ring_o<32><<<512, 256, 0, stream>>>(AO, wob, out, bo);
}

// Round 13
// 93.214 us; speedup vs baseline: 1.3528x; 1.0603x over previous
//
#include <hip/hip_runtime.h>
#include <hip/hip_bf16.h>
#include <stdint.h>

#define B_   4
#define SEQ_ 1024
#define DM   1024
#define H_   16
#define HD   64

typedef __bf16 bf16;
typedef __bf16 bf16x8 __attribute__((ext_vector_type(8)));
typedef __bf16 bf16x4v __attribute__((ext_vector_type(4)));
typedef __bf16 bf16x2 __attribute__((ext_vector_type(2)));
typedef float  f32x4 __attribute__((ext_vector_type(4)));

__device__ __forceinline__ void gl_lds16(const void* g, void* s_uniform) {
    __builtin_amdgcn_global_load_lds(
        (const __attribute__((address_space(1))) uint32_t*)g,
        (__attribute__((address_space(3))) uint32_t*)s_uniform,
        16, 0, 0);
}

// ---------------------------------------------------------------------------
// prep: fp32 -> bf16 casts + T5 bias table [h][dist] (pre-scaled by log2e)
// ---------------------------------------------------------------------------
__global__ __launch_bounds__(256) void prep_kernel(
    const float* __restrict__ x, const float* __restrict__ Wq,
    const float* __restrict__ Wk, const float* __restrict__ Wv,
    const float* __restrict__ Wo, const float* __restrict__ rel,
    bf16* __restrict__ xb, bf16* __restrict__ wqkvb, bf16* __restrict__ wob,
    float* __restrict__ biasT)
{
    int tid = blockIdx.x * 256 + threadIdx.x;
    int stride = gridDim.x * 256;

    for (int i = tid; i < (B_*SEQ_*DM)/4; i += stride) {
        float4 v = ((const float4*)x)[i];
        bf16x4v o; o[0]=(bf16)v.x; o[1]=(bf16)v.y; o[2]=(bf16)v.z; o[3]=(bf16)v.w;
        ((bf16x4v*)xb)[i] = o;
    }
    for (int i = tid; i < (3*DM*DM)/4; i += stride) {
        int n = i >> 8, k4 = i & 255;
        const float* src = (n < 1024) ? Wq : (n < 2048) ? Wk : Wv;
        float4 v = ((const float4*)(src + (size_t)(n & 1023) * DM))[k4];
        bf16x4v o; o[0]=(bf16)v.x; o[1]=(bf16)v.y; o[2]=(bf16)v.z; o[3]=(bf16)v.w;
        ((bf16x4v*)wqkvb)[i] = o;
    }
    for (int i = tid; i < (DM*DM)/4; i += stride) {
        float4 v = ((const float4*)Wo)[i];
        bf16x4v o; o[0]=(bf16)v.x; o[1]=(bf16)v.y; o[2]=(bf16)v.z; o[3]=(bf16)v.w;
        ((bf16x4v*)wob)[i] = o;
    }
    for (int i = tid; i < H_ * SEQ_; i += stride) {
        int h = i >> 10, dist = i & 1023;
        int bkt;
        if (dist < 16) {
            bkt = dist;
        } else {
            float r = logf((float)dist * (1.0f/16.0f)) / logf(8.0f) * 16.0f;
            int vb = 16 + (int)r;
            bkt = vb > 31 ? 31 : vb;
        }
        biasT[i] = rel[bkt * H_ + h] * (0.125f * 1.4426950408889634f);
    }
}

// ---------------------------------------------------------------------------
// Ring GEMM v3 (QKV): C = A @ B^T, BM=256, BN=128, BK=32, 512 thr (8 waves
// 4Mx2N, wave tile 64x64), 3 LDS buffers (72 KB), depth-2 ring, counted
// vmcnt(3), chunk-XOR swizzle. Grid 384 (full coverage, capacity 2/CU).
// Two-level rectangle XCD swizzle (4ty x [2x6]tx). Q scaled by log2e.
// Q/K direct scatter; V via LDS transpose (256x128) -> coalesced Vt.
// ---------------------------------------------------------------------------
template<int NT>
__global__ __launch_bounds__(512, 4) void gemm_ring2(
    const bf16* __restrict__ Ag, const bf16* __restrict__ Bg,
    bf16* __restrict__ qb, bf16* __restrict__ kb, bf16* __restrict__ vtb,
    const float* __restrict__ bq, const float* __restrict__ bk,
    const float* __restrict__ bv)
{
    __shared__ __align__(16) bf16 tile[3][384 * 32];   // 3 x 24 KB

    const int t = threadIdx.x;
    const int lane = t & 63, w = t >> 6;
    const int wr = w >> 1, wc = w & 1;         // 4M x 2N wave grid
    const int row_l = lane & 15;
    const int lg = lane >> 4;

    // two-level rectangle XCD swizzle: XCD region 4ty x 12tx, sub 4x6
    int xcd = blockIdx.x & 7;
    int idx = blockIdx.x >> 3;                 // 0..47
    int sub = idx / 24, rem = idx % 24;
    int ty = (xcd >> 1) * 4 + rem / 6;
    int tx = (xcd & 1) * 12 + sub * 6 + rem % 6;
    const int m0 = ty * 256, n0 = tx * 128;

    f32x4 acc[4][4] = {};

    auto STAGE = [&](int buf, int kt) {
        bf16* dst = &tile[buf][0];
        #pragma unroll
        for (int i = 0; i < 3; ++i) {
            int e = i * 4096 + t * 8;
            int r = e >> 5;                        // 0..383
            int csw = ((t & 3) ^ (r & 3)) << 3;    // inverse-swizzled src col
            const bf16* src = (r < 256)
                ? (Ag + (long)(m0 + r) * 1024 + kt * 32 + csw)
                : (Bg + (long)(n0 + r - 256) * 1024 + kt * 32 + csw);
            gl_lds16(src, dst + i * 4096 + w * 512);
        }
    };

    auto COMPUTE = [&](int buf) {
        const bf16* bp = &tile[buf][0];
        bf16x8 af[4], bfr[4];
        #pragma unroll
        for (int m = 0; m < 4; ++m) {
            int ra = wr * 64 + m * 16 + row_l;
            af[m] = *(const bf16x8*)&bp[ra * 32 + ((lg ^ (ra & 3)) << 3)];
        }
        #pragma unroll
        for (int n = 0; n < 4; ++n) {
            int rb = 256 + wc * 64 + n * 16 + row_l;
            bfr[n] = *(const bf16x8*)&bp[rb * 32 + ((lg ^ (rb & 3)) << 3)];
        }
        #pragma unroll
        for (int m = 0; m < 4; ++m)
            #pragma unroll
            for (int n = 0; n < 4; ++n)
                acc[m][n] = __builtin_amdgcn_mfma_f32_16x16x32_bf16(
                    af[m], bfr[n], acc[m][n], 0, 0, 0);
    };

    STAGE(0, 0); STAGE(1, 1);
    asm volatile("s_waitcnt vmcnt(3)" ::: "memory");
    __builtin_amdgcn_s_barrier();

    int cb = 0;
    for (int kt = 0; kt < NT; ++kt) {
        int sb = cb - 1; if (sb < 0) sb += 3;     // (kt+2) % 3
        if (kt + 2 < NT) STAGE(sb, kt + 2);
        COMPUTE(cb);
        if (kt + 2 < NT) { asm volatile("s_waitcnt vmcnt(3)" ::: "memory"); }
        else             { asm volatile("s_waitcnt vmcnt(0)" ::: "memory"); }
        __builtin_amdgcn_s_barrier();
        cb = (cb + 1 == 3) ? 0 : cb + 1;
    }

    const int rbase = (lane >> 4) * 4;

    if (n0 < 2048) {
        // ---- Q/K epilogue: bias add (+log2e fold on Q), direct scatter
        #pragma unroll
        for (int m = 0; m < 4; ++m) {
            #pragma unroll
            for (int n = 0; n < 4; ++n) {
                #pragma unroll
                for (int g = 0; g < 4; ++g) {
                    int gm = m0 + wr * 64 + m * 16 + rbase + g;
                    int gn = n0 + wc * 64 + n * 16 + row_l;
                    int which = gn >> 10, nn = gn & 1023;
                    int h = nn >> 6, d = nn & 63;
                    int b = gm >> 10, s = gm & 1023;
                    float v = acc[m][n][g] + ((which == 0) ? bq[nn] : bk[nn]);
                    if (which == 0) v *= 1.4426950408889634f;
                    bf16 bv16 = (bf16)v;
                    if (which == 0)
                        qb[((long)(b*H_ + h)*SEQ_ + s)*HD + d] = bv16;
                    else
                        kb[((long)(b*H_ + h)*SEQ_ + s)*HD + d] = bv16;
                }
            }
        }
    } else {
        // ---- V epilogue: 256x128 LDS transpose (XOR-staggered) -> Vt
        bf16* lt = &tile[0][0];                   // 64 KB within 72 KB
        #pragma unroll
        for (int m = 0; m < 4; ++m) {
            #pragma unroll
            for (int n = 0; n < 4; ++n) {
                int nl = wc * 64 + n * 16 + row_l;        // 0..127
                int mlb = wr * 64 + m * 16 + rbase;       // even
                float bvv = bv[(n0 & 1023) + nl];
                #pragma unroll
                for (int g2 = 0; g2 < 2; ++g2) {
                    bf16x2 pk;
                    pk[0] = (bf16)(acc[m][n][2*g2]     + bvv);
                    pk[1] = (bf16)(acc[m][n][2*g2 + 1] + bvv);
                    int ml = mlb + 2 * g2;                // 0..255
                    int byte = nl * 512 + ((ml * 2) ^ ((nl & 15) << 4));
                    *(bf16x2*)((char*)lt + byte) = pk;
                }
            }
        }
        __syncthreads();
        {
            int nl = t >> 2, sc = t & 3;          // col 0..127, s-chunk 0..3
            int nn = (n0 & 1023) + nl;
            int h = nn >> 6, d = nn & 63;
            int b = m0 >> 10, s0 = (m0 & 1023) + sc * 64;
            bf16* dst = vtb + ((long)(b*H_ + h)*HD + d)*SEQ_ + s0;
            #pragma unroll
            for (int i = 0; i < 8; ++i) {
                int byte = nl * 512 + ((sc * 128 + i * 16) ^ ((nl & 15) << 4));
                *(float4*)(dst + i * 8) = *(const float4*)((char*)lt + byte);
            }
        }
    }
}

// ---------------------------------------------------------------------------
// Ring GEMM (out-proj): BM=128, BN=64, BK=32, 3 bufs, counted vmcnt.
// ---------------------------------------------------------------------------
template<int NT>
__global__ __launch_bounds__(256, 2) void gemm_ring_o(
    const bf16* __restrict__ Ag, const bf16* __restrict__ Bg,
    float* __restrict__ outp, const float* __restrict__ bo)
{
    __shared__ __align__(16) bf16 tile[3][192 * 32];

    const int t = threadIdx.x;
    const int lane = t & 63, w = t >> 6;
    const int wr = w >> 1, wc = w & 1;
    const int row_l = lane & 15;
    const int lg = lane >> 4;

    int xcd = blockIdx.x & 7;
    int idx = blockIdx.x >> 3;
    int ty = (xcd >> 1) * 8 + (idx >> 3);
    int tx = (xcd & 1) * 8 + (idx & 7);
    const int m0 = ty * 128, n0 = tx * 64;

    f32x4 acc[4][2] = {};

    auto STAGE = [&](int buf, int kt) {
        bf16* dst = &tile[buf][0];
        #pragma unroll
        for (int i = 0; i < 3; ++i) {
            int e = i * 2048 + t * 8;
            int r = e >> 5;
            int csw = ((t & 3) ^ (r & 3)) << 3;
            const bf16* src = (r < 128)
                ? (Ag + (long)(m0 + r) * 1024 + kt * 32 + csw)
                : (Bg + (long)(n0 + r - 128) * 1024 + kt * 32 + csw);
            gl_lds16(src, dst + i * 2048 + w * 512);
        }
    };

    auto COMPUTE = [&](int buf) {
        const bf16* bp = &tile[buf][0];
        bf16x8 af[4], bfr[2];
        #pragma unroll
        for (int m = 0; m < 4; ++m) {
            int ra = wr * 64 + m * 16 + row_l;
            af[m] = *(const bf16x8*)&bp[ra * 32 + ((lg ^ (ra & 3)) << 3)];
        }
        #pragma unroll
        for (int n = 0; n < 2; ++n) {
            int rb = 128 + wc * 32 + n * 16 + row_l;
            bfr[n] = *(const bf16x8*)&bp[rb * 32 + ((lg ^ (rb & 3)) << 3)];
        }
        #pragma unroll
        for (int m = 0; m < 4; ++m)
            #pragma unroll
            for (int n = 0; n < 2; ++n)
                acc[m][n] = __builtin_amdgcn_mfma_f32_16x16x32_bf16(
                    af[m], bfr[n], acc[m][n], 0, 0, 0);
    };

    STAGE(0, 0); STAGE(1, 1);
    asm volatile("s_waitcnt vmcnt(3)" ::: "memory");
    __builtin_amdgcn_s_barrier();

    int cb = 0;
    for (int kt = 0; kt < NT; ++kt) {
        int sb = cb - 1; if (sb < 0) sb += 3;
        if (kt + 2 < NT) STAGE(sb, kt + 2);
        COMPUTE(cb);
        if (kt + 2 < NT) { asm volatile("s_waitcnt vmcnt(3)" ::: "memory"); }
        else             { asm volatile("s_waitcnt vmcnt(0)" ::: "memory"); }
        __builtin_amdgcn_s_barrier();
        cb = (cb + 1 == 3) ? 0 : cb + 1;
    }

    const int rbase = (lane >> 4) * 4;
    #pragma unroll
    for (int m = 0; m < 4; ++m) {
        #pragma unroll
        for (int n = 0; n < 2; ++n) {
            #pragma unroll
            for (int g = 0; g < 4; ++g) {
                int gm = m0 + wr * 64 + m * 16 + rbase + g;
                int gn = n0 + wc * 32 + n * 16 + row_l;
                outp[(long)gm * DM + gn] = acc[m][n][g] + bo[gn];
            }
        }
    }
}

// ---------------------------------------------------------------------------
// Flash attention v8: 512 thr (pair {p,15-p}, waves 0-3 lo / 4-7 hi),
// 3-buffer K/V ring with counted vmcnt(2) (no per-step drain), XOR-packed
// Ps (16 KB), diagonal-only mask fast path, CU-balanced pair map,
// static-shift softmax with exp2 (Q/bias pre-scaled by log2e).
// ---------------------------------------------------------------------------
__global__ __launch_bounds__(512, 4) void attn_kernel(
    const bf16* __restrict__ Qb, const bf16* __restrict__ Kb,
    const bf16* __restrict__ Vtb, const float* __restrict__ biasT,
    bf16* __restrict__ AO)
{
    __shared__ __align__(16) bf16 Ks[3][64 * 64];    // 24 KB
    __shared__ __align__(16) bf16 Vs[3][64 * 64];    // 24 KB
    __shared__ __align__(16) bf16 Ps[8][16 * 64];    // 16 KB
    __shared__ float biasS[SEQ_];                    // 4 KB  => 68 KB

    int t = threadIdx.x;
    int lane = t & 63, w = t >> 6;

    // decode: XCD-local groups; balanced pair map (same-CU sums = 25 steps)
    int bid = blockIdx.x;
    int xcd = bid & 7;
    int rest = bid >> 3;            // 0..63
    int g = xcd * 8 + (rest & 7);
    int pe = rest >> 3;             // 0..7
    int p = (pe < 4) ? pe : 11 - pe;
    int qt_hi = 15 - p;
    int h = g & 15, b = g >> 4;

    int qtw = (w < 4) ? p : qt_hi;          // this wave's q-tile
    int row0 = qtw * 64 + (w & 3) * 16;

    int row_l = lane & 15;
    int ksl = (lane >> 4) * 8;
    int rbase = (lane >> 4) * 4;

    const bf16* Kbase = Kb + (long)g * SEQ_ * HD;
    const bf16* Vbase = Vtb + (long)g * HD * SEQ_;

    auto stageKV = [&](int jt) {
        int sl = jt % 3;
        int e = t * 8;
        int r = e >> 6;
        int csw = ((((e >> 3) & 7) ^ (r & 7)) << 3);
        gl_lds16(Kbase + (long)(jt * 64 + r) * HD + csw, &Ks[sl][0] + w * 512);
        gl_lds16(Vbase + (long)r * SEQ_ + jt * 64 + csw, &Vs[sl][0] + w * 512);
    };

    stageKV(0);
    stageKV(1);
    if (t < 256)
        ((float4*)biasS)[t] = ((const float4*)(biasT + (long)h * SEQ_))[t];

    const bf16* Qp = Qb + ((long)g * SEQ_ + row0) * HD;
    bf16x8 qf0 = *(const bf16x8*)&Qp[row_l * HD + ksl];
    bf16x8 qf1 = *(const bf16x8*)&Qp[row_l * HD + 32 + ksl];

    f32x4 oacc[4] = {};
    float lsum[4] = {0.f, 0.f, 0.f, 0.f};
    int ir[4];
    #pragma unroll
    for (int q = 0; q < 4; ++q) ir[q] = row0 + rbase + q;

    __syncthreads();   // prologue: stages 0,1 + biasS all visible

    char* psw = (char*)&Ps[w][0];
    int prswz = (row_l & 7) << 4;

    for (int jt = 0; jt <= qt_hi; ++jt) {
        if (jt < qt_hi) { asm volatile("s_waitcnt vmcnt(2)" ::: "memory"); }
        else            { asm volatile("s_waitcnt vmcnt(0)" ::: "memory"); }
        __builtin_amdgcn_s_barrier();
        if (jt + 2 <= qt_hi) stageKV(jt + 2);

        if (jt <= qtw) {
            int sl = jt % 3;
            const bf16* kb_ = &Ks[sl][0];
            const bf16* vb_ = &Vs[sl][0];

            // QK^T
            f32x4 s[4] = {};
            __builtin_amdgcn_s_setprio(1);
            #pragma unroll
            for (int f = 0; f < 4; ++f) {
                int ra = f * 16 + row_l;
                int a0 = (ra * 64 + ksl)      ^ ((ra & 7) << 3);
                int a1 = (ra * 64 + 32 + ksl) ^ ((ra & 7) << 3);
                bf16x8 kf0 = *(const bf16x8*)&kb_[a0];
                bf16x8 kf1 = *(const bf16x8*)&kb_[a1];
                s[f] = __builtin_amdgcn_mfma_f32_16x16x32_bf16(qf0, kf0, s[f], 0,0,0);
                s[f] = __builtin_amdgcn_mfma_f32_16x16x32_bf16(qf1, kf1, s[f], 0,0,0);
            }
            __builtin_amdgcn_s_setprio(0);

            // softmax: P = exp2(S' + bias'); interior tiles skip the mask
            if (jt < qtw) {
                #pragma unroll
                for (int f = 0; f < 4; ++f) {
                    int j = jt * 64 + f * 16 + row_l;
                    #pragma unroll
                    for (int q = 0; q < 4; ++q) {
                        float sv = s[f][q] + biasS[ir[q] - j];
                        float pexp = exp2f(sv);
                        lsum[q] += pexp;
                        int pr = rbase + q;
                        int byte = pr * 128 + ((((f*16 + row_l) * 2)) ^ ((pr & 7) << 4));
                        *(bf16*)(psw + byte) = (bf16)pexp;
                    }
                }
            } else {
                #pragma unroll
                for (int f = 0; f < 4; ++f) {
                    int j = jt * 64 + f * 16 + row_l;
                    #pragma unroll
                    for (int q = 0; q < 4; ++q) {
                        float sv = (j <= ir[q]) ? (s[f][q] + biasS[ir[q] - j]) : -1e30f;
                        float pexp = exp2f(sv);
                        lsum[q] += pexp;
                        int pr = rbase + q;
                        int byte = pr * 128 + ((((f*16 + row_l) * 2)) ^ ((pr & 7) << 4));
                        *(bf16*)(psw + byte) = (bf16)pexp;
                    }
                }
            }
            bf16x8 pf0 = *(const bf16x8*)(psw + row_l * 128 + ((ksl * 2) ^ prswz));
            bf16x8 pf1 = *(const bf16x8*)(psw + row_l * 128 + ((64 + ksl * 2) ^ prswz));

            // PV
            __builtin_amdgcn_s_setprio(1);
            #pragma unroll
            for (int db = 0; db < 4; ++db) {
                int ra = db * 16 + row_l;
                int a0 = (ra * 64 + ksl)      ^ ((ra & 7) << 3);
                int a1 = (ra * 64 + 32 + ksl) ^ ((ra & 7) << 3);
                bf16x8 vf0 = *(const bf16x8*)&vb_[a0];
                bf16x8 vf1 = *(const bf16x8*)&vb_[a1];
                oacc[db] = __builtin_amdgcn_mfma_f32_16x16x32_bf16(pf0, vf0, oacc[db], 0,0,0);
                oacc[db] = __builtin_amdgcn_mfma_f32_16x16x32_bf16(pf1, vf1, oacc[db], 0,0,0);
            }
            __builtin_amdgcn_s_setprio(0);
        }
    }

    // epilogue: row-sum reduce across the 16 k-col lanes, write AO
    #pragma unroll
    for (int q = 0; q < 4; ++q) {
        float l = lsum[q];
        #pragma unroll
        for (int off = 1; off < 16; off <<= 1) l += __shfl_xor(l, off);
        float inv = 1.0f / l;
        long base = ((long)(b * SEQ_ + ir[q])) * DM + h * HD;
        #pragma unroll
        for (int db = 0; db < 4; ++db)
            AO[base + db * 16 + row_l] = (bf16)(oacc[db][q] * inv);
    }
}

// ---------------------------------------------------------------------------
extern "C" void kernel_launch(void* const* d_in, const int* in_sizes, int n_in,
                              void* d_out, int out_size, void* d_ws, size_t ws_size,
                              hipStream_t stream)
{
    const float* x   = (const float*)d_in[0];
    const float* Wq  = (const float*)d_in[1];
    const float* bq  = (const float*)d_in[2];
    const float* Wk  = (const float*)d_in[3];
    const float* bk  = (const float*)d_in[4];
    const float* Wv  = (const float*)d_in[5];
    const float* bv  = (const float*)d_in[6];
    const float* Wo  = (const float*)d_in[7];
    const float* bo  = (const float*)d_in[8];
    const float* rel = (const float*)d_in[9];
    float* out = (float*)d_out;

    char* ws = (char*)d_ws;
    bf16* xb    = (bf16*)ws;  ws += (size_t)B_*SEQ_*DM * 2;
    bf16* wqkvb = (bf16*)ws;  ws += (size_t)3*DM*DM * 2;
    bf16* wob   = (bf16*)ws;  ws += (size_t)DM*DM * 2;
    float* biasT= (float*)ws; ws += (size_t)H_*SEQ_ * 4;
    bf16* Qb    = (bf16*)ws;  ws += (size_t)B_*H_*SEQ_*HD * 2;
    bf16* Kb2   = (bf16*)ws;  ws += (size_t)B_*H_*SEQ_*HD * 2;
    bf16* Vtb   = (bf16*)ws;  ws += (size_t)B_*H_*SEQ_*HD * 2;
    bf16* AO    = (bf16*)ws;  ws += (size_t)B_*SEQ_*DM * 2;

    prep_kernel<<<2048, 256, 0, stream>>>(x, Wq, Wk, Wv, Wo, rel,
                                          xb, wqkvb, wob, biasT);

    // QKV: M=4096, N=3072 -> 16 x 24 = 384 blocks of 256x128
    gemm_ring2<32><<<384, 512, 0, stream>>>(
        xb, wqkvb, Qb, Kb2, Vtb, bq, bk, bv);

    attn_kernel<<<512, 512, 0, stream>>>(Qb, Kb2, Vtb, biasT, AO);

    // out-proj: M=4096, N=1024 -> 32 x 16 = 512 blocks of 128x64
    gemm_ring_o<32><<<512, 256, 0, stream>>>(AO, wob, out, bo);
}

// Round 14
// 92.474 us; speedup vs baseline: 1.3636x; 1.0080x over previous
//
#include <hip/hip_runtime.h>
#include <hip/hip_bf16.h>
#include <stdint.h>

#define B_   4
#define SEQ_ 1024
#define DM   1024
#define H_   16
#define HD   64

typedef __bf16 bf16;
typedef __bf16 bf16x8 __attribute__((ext_vector_type(8)));
typedef __bf16 bf16x4v __attribute__((ext_vector_type(4)));
typedef __bf16 bf16x2 __attribute__((ext_vector_type(2)));
typedef float  f32x4 __attribute__((ext_vector_type(4)));

__device__ __forceinline__ void gl_lds16(const void* g, void* s_uniform) {
    __builtin_amdgcn_global_load_lds(
        (const __attribute__((address_space(1))) uint32_t*)g,
        (__attribute__((address_space(3))) uint32_t*)s_uniform,
        16, 0, 0);
}

// ---------------------------------------------------------------------------
// prep: fp32 -> bf16 casts + T5 bias table [h][dist] (pre-scaled by log2e)
// ---------------------------------------------------------------------------
__global__ __launch_bounds__(256) void prep_kernel(
    const float* __restrict__ x, const float* __restrict__ Wq,
    const float* __restrict__ Wk, const float* __restrict__ Wv,
    const float* __restrict__ Wo, const float* __restrict__ rel,
    bf16* __restrict__ xb, bf16* __restrict__ wqkvb, bf16* __restrict__ wob,
    float* __restrict__ biasT)
{
    int tid = blockIdx.x * 256 + threadIdx.x;
    int stride = gridDim.x * 256;

    for (int i = tid; i < (B_*SEQ_*DM)/4; i += stride) {
        float4 v = ((const float4*)x)[i];
        bf16x4v o; o[0]=(bf16)v.x; o[1]=(bf16)v.y; o[2]=(bf16)v.z; o[3]=(bf16)v.w;
        ((bf16x4v*)xb)[i] = o;
    }
    for (int i = tid; i < (3*DM*DM)/4; i += stride) {
        int n = i >> 8, k4 = i & 255;
        const float* src = (n < 1024) ? Wq : (n < 2048) ? Wk : Wv;
        float4 v = ((const float4*)(src + (size_t)(n & 1023) * DM))[k4];
        bf16x4v o; o[0]=(bf16)v.x; o[1]=(bf16)v.y; o[2]=(bf16)v.z; o[3]=(bf16)v.w;
        ((bf16x4v*)wqkvb)[i] = o;
    }
    for (int i = tid; i < (DM*DM)/4; i += stride) {
        float4 v = ((const float4*)Wo)[i];
        bf16x4v o; o[0]=(bf16)v.x; o[1]=(bf16)v.y; o[2]=(bf16)v.z; o[3]=(bf16)v.w;
        ((bf16x4v*)wob)[i] = o;
    }
    for (int i = tid; i < H_ * SEQ_; i += stride) {
        int h = i >> 10, dist = i & 1023;
        int bkt;
        if (dist < 16) {
            bkt = dist;
        } else {
            float r = logf((float)dist * (1.0f/16.0f)) / logf(8.0f) * 16.0f;
            int vb = 16 + (int)r;
            bkt = vb > 31 ? 31 : vb;
        }
        biasT[i] = rel[bkt * H_ + h] * (0.125f * 1.4426950408889634f);
    }
}

// ---------------------------------------------------------------------------
// 8-phase pipelined GEMM (QKV), m201 template, NO sched_barriers:
// BM=BN=256, BK=64, 512 thr (8 waves 2Mx4N, wave tile 128x64), LDS 128 KB
// (2 dbuf x 2 half x 128x64 for A and B). Per phase: {ds_read subtile,
// stage 1 half-tile (2 gl_lds), s_barrier, setprio(1) 16 MFMA setprio(0)},
// counted vmcnt(4) after phases 3 and 7 only (ledger-derived; never 0 in
// steady state). Grid 192, 1 block/CU. Chunk-XOR swizzle both sides.
// Epilogue: Q (log2e-folded) / K direct scatter; V via 256x256 LDS
// transpose (reusing the 128 KB) -> coalesced Vt stores.
// ---------------------------------------------------------------------------
template<int NT>   // NT = 16 K-tiles (K=1024, BK=64)
__global__ __launch_bounds__(512, 2) void gemm8q(
    const bf16* __restrict__ Ag, const bf16* __restrict__ Bg,
    bf16* __restrict__ qb, bf16* __restrict__ kb, bf16* __restrict__ vtb,
    const float* __restrict__ bq, const float* __restrict__ bk,
    const float* __restrict__ bv)
{
    __shared__ __align__(16) bf16 sh[65536];     // 128 KB
    bf16* As = sh;                               // [2 dbuf][2 half][128][64]
    bf16* Bs = sh + 32768;

    const int t = threadIdx.x;
    const int lane = t & 63, w = t >> 6;
    const int wr = w >> 2, wc = w & 3;           // 2M x 4N wave grid
    const int row_l = lane & 15;
    const int lg = lane >> 4;

    // XCD rectangle swizzle: 192 = 8 x 24; region 4ty x 6tx, 2 sub-phases 4x3
    int xcd = blockIdx.x & 7;
    int idx = blockIdx.x >> 3;                   // 0..23
    int sub = idx / 12, rem = idx % 12;
    int ty = (xcd >> 1) * 4 + rem / 3;
    int tx = (xcd & 1) * 6 + sub * 3 + rem % 3;
    const int m0 = ty * 256, n0 = tx * 256;

    f32x4 acc[8][4] = {};

    // stage one 128x64 half-tile (2 gl_lds per thread), pre-swizzled source
    auto stageH = [&](bf16* lbase, const bf16* gbase, int grow0, int kt) {
        #pragma unroll
        for (int j = 0; j < 2; ++j) {
            int rl = j * 64 + (t >> 3);
            int csw = ((t & 7) ^ (rl & 7)) << 3;
            gl_lds16(gbase + (long)(grow0 + rl) * 1024 + kt * 64 + csw,
                     lbase + j * 4096 + w * 512);
        }
    };

    // ---- prologue: tile0 (A+B) + B(tile1); wait tile0, keep B1 in flight
    stageH(As,               Ag, m0,        0);
    stageH(As + 8192,        Ag, m0 + 128,  0);
    stageH(Bs,               Bg, n0,        0);
    stageH(Bs + 8192,        Bg, n0 + 128,  0);
    stageH(Bs + 16384,       Bg, n0,        1);
    stageH(Bs + 16384 + 8192,Bg, n0 + 128,  1);
    asm volatile("s_waitcnt vmcnt(4)" ::: "memory");
    __builtin_amdgcn_s_barrier();

    for (int i = 0; i < NT/2; ++i) {
        const bool more = (i + 1 < NT/2);
        #pragma unroll
        for (int ht = 0; ht < 2; ++ht) {         // K-tiles 2i (buf0), 2i+1 (buf1)
            const bf16* Ad = As + (ht ? 16384 : 0);
            const bf16* Bd = Bs + (ht ? 16384 : 0);
            bf16x8 bfv[4][2];
            #pragma unroll
            for (int mh = 0; mh < 4; ++mh) {
                // ---- ds-load register subtile
                bf16x8 afr[2][2];
                if (mh == 0) {
                    #pragma unroll
                    for (int n = 0; n < 4; ++n)
                        #pragma unroll
                        for (int ks = 0; ks < 2; ++ks) {
                            int rb = wc * 64 + n * 16 + row_l;
                            int ch = ks * 4 + lg;
                            bfv[n][ks] = *(const bf16x8*)&Bd[rb * 64 + ((ch ^ (rb & 7)) << 3)];
                        }
                }
                #pragma unroll
                for (int mm = 0; mm < 2; ++mm)
                    #pragma unroll
                    for (int ks = 0; ks < 2; ++ks) {
                        int ra = wr * 128 + mh * 32 + mm * 16 + row_l;
                        int ch = ks * 4 + lg;
                        afr[mm][ks] = *(const bf16x8*)&Ad[ra * 64 + ((ch ^ (ra & 7)) << 3)];
                    }

                // ---- stage 1 half-tile per phase (ledger-verified targets)
                int p = ht * 4 + mh;
                if (p == 0)      stageH(As + 16384,        Ag, m0,       2*i+1);
                else if (p == 1) stageH(As + 16384 + 8192, Ag, m0 + 128, 2*i+1);
                else if (more) {
                    if (p == 2)      stageH(Bs,               Bg, n0,       2*i+2);
                    else if (p == 3) stageH(Bs + 8192,        Bg, n0 + 128, 2*i+2);
                    else if (p == 4) stageH(As,               Ag, m0,       2*i+2);
                    else if (p == 5) stageH(As + 8192,        Ag, m0 + 128, 2*i+2);
                    else if (p == 6) stageH(Bs + 16384,       Bg, n0,       2*i+3);
                    else             stageH(Bs + 16384 + 8192,Bg, n0 + 128, 2*i+3);
                }

                __builtin_amdgcn_s_barrier();
                __builtin_amdgcn_s_setprio(1);
                #pragma unroll
                for (int mm = 0; mm < 2; ++mm)
                    #pragma unroll
                    for (int n = 0; n < 4; ++n)
                        #pragma unroll
                        for (int ks = 0; ks < 2; ++ks)
                            acc[mh*2+mm][n] = __builtin_amdgcn_mfma_f32_16x16x32_bf16(
                                afr[mm][ks], bfv[n][ks], acc[mh*2+mm][n], 0, 0, 0);
                __builtin_amdgcn_s_setprio(0);
                if (p == 3 || p == 7) {
                    if (more) { asm volatile("s_waitcnt vmcnt(4)" ::: "memory"); }
                    else      { asm volatile("s_waitcnt vmcnt(0)" ::: "memory"); }
                }
                __builtin_amdgcn_s_barrier();
            }
        }
    }

    const int rbase = (lane >> 4) * 4;

    if (n0 < 2048) {
        // ---- Q/K epilogue: bias add (+log2e fold on Q), direct scatter
        #pragma unroll
        for (int m = 0; m < 8; ++m) {
            #pragma unroll
            for (int n = 0; n < 4; ++n) {
                #pragma unroll
                for (int g = 0; g < 4; ++g) {
                    int gm = m0 + wr * 128 + m * 16 + rbase + g;
                    int gn = n0 + wc * 64 + n * 16 + row_l;
                    int which = gn >> 10, nn = gn & 1023;
                    int h = nn >> 6, d = nn & 63;
                    int b = gm >> 10, s = gm & 1023;
                    float v = acc[m][n][g] + ((which == 0) ? bq[nn] : bk[nn]);
                    if (which == 0) v *= 1.4426950408889634f;
                    bf16 bv16 = (bf16)v;
                    if (which == 0)
                        qb[((long)(b*H_ + h)*SEQ_ + s)*HD + d] = bv16;
                    else
                        kb[((long)(b*H_ + h)*SEQ_ + s)*HD + d] = bv16;
                }
            }
        }
    } else {
        // ---- V epilogue: 256x256 LDS transpose (XOR-staggered, reuse sh)
        __builtin_amdgcn_s_barrier();
        #pragma unroll
        for (int m = 0; m < 8; ++m) {
            #pragma unroll
            for (int n = 0; n < 4; ++n) {
                int col = wc * 64 + n * 16 + row_l;          // 0..255 (v-dim)
                int mlb = wr * 128 + m * 16 + rbase;         // even row base
                float bvv = bv[(n0 & 1023) + col];
                #pragma unroll
                for (int g2 = 0; g2 < 2; ++g2) {
                    bf16x2 pk;
                    pk[0] = (bf16)(acc[m][n][2*g2]     + bvv);
                    pk[1] = (bf16)(acc[m][n][2*g2 + 1] + bvv);
                    int row = mlb + 2 * g2;                  // 0..255 (s-dim)
                    int byte = col * 512 + ((row * 2) ^ ((col & 15) << 4));
                    *(bf16x2*)((char*)sh + byte) = pk;
                }
            }
        }
        __syncthreads();
        {
            int cr = t >> 1, sc = t & 1;                     // col, chunk-half
            int nn = (n0 & 1023) + cr;
            int h = nn >> 6, d = nn & 63;
            int b = m0 >> 10;
            bf16* dst = vtb + ((long)(b*H_ + h)*HD + d)*SEQ_ + (m0 & 1023);
            #pragma unroll
            for (int ii = 0; ii < 16; ++ii) {
                int chunk = sc * 16 + ii;                    // 0..31 (8 s-rows each)
                int byte = cr * 512 + ((chunk * 16) ^ ((cr & 15) << 4));
                *(float4*)(dst + chunk * 8) = *(const float4*)((char*)sh + byte);
            }
        }
    }
}

// ---------------------------------------------------------------------------
// Ring GEMM (out-proj): BM=128, BN=64, BK=32, 3 bufs, counted vmcnt.
// ---------------------------------------------------------------------------
template<int NT>
__global__ __launch_bounds__(256, 2) void gemm_ring_o(
    const bf16* __restrict__ Ag, const bf16* __restrict__ Bg,
    float* __restrict__ outp, const float* __restrict__ bo)
{
    __shared__ __align__(16) bf16 tile[3][192 * 32];

    const int t = threadIdx.x;
    const int lane = t & 63, w = t >> 6;
    const int wr = w >> 1, wc = w & 1;
    const int row_l = lane & 15;
    const int lg = lane >> 4;

    int xcd = blockIdx.x & 7;
    int idx = blockIdx.x >> 3;
    int ty = (xcd >> 1) * 8 + (idx >> 3);
    int tx = (xcd & 1) * 8 + (idx & 7);
    const int m0 = ty * 128, n0 = tx * 64;

    f32x4 acc[4][2] = {};

    auto STAGE = [&](int buf, int kt) {
        bf16* dst = &tile[buf][0];
        #pragma unroll
        for (int i = 0; i < 3; ++i) {
            int e = i * 2048 + t * 8;
            int r = e >> 5;
            int csw = ((t & 3) ^ (r & 3)) << 3;
            const bf16* src = (r < 128)
                ? (Ag + (long)(m0 + r) * 1024 + kt * 32 + csw)
                : (Bg + (long)(n0 + r - 128) * 1024 + kt * 32 + csw);
            gl_lds16(src, dst + i * 2048 + w * 512);
        }
    };

    auto COMPUTE = [&](int buf) {
        const bf16* bp = &tile[buf][0];
        bf16x8 af[4], bfr[2];
        #pragma unroll
        for (int m = 0; m < 4; ++m) {
            int ra = wr * 64 + m * 16 + row_l;
            af[m] = *(const bf16x8*)&bp[ra * 32 + ((lg ^ (ra & 3)) << 3)];
        }
        #pragma unroll
        for (int n = 0; n < 2; ++n) {
            int rb = 128 + wc * 32 + n * 16 + row_l;
            bfr[n] = *(const bf16x8*)&bp[rb * 32 + ((lg ^ (rb & 3)) << 3)];
        }
        #pragma unroll
        for (int m = 0; m < 4; ++m)
            #pragma unroll
            for (int n = 0; n < 2; ++n)
                acc[m][n] = __builtin_amdgcn_mfma_f32_16x16x32_bf16(
                    af[m], bfr[n], acc[m][n], 0, 0, 0);
    };

    STAGE(0, 0); STAGE(1, 1);
    asm volatile("s_waitcnt vmcnt(3)" ::: "memory");
    __builtin_amdgcn_s_barrier();

    int cb = 0;
    for (int kt = 0; kt < NT; ++kt) {
        int sb = cb - 1; if (sb < 0) sb += 3;
        if (kt + 2 < NT) STAGE(sb, kt + 2);
        COMPUTE(cb);
        if (kt + 2 < NT) { asm volatile("s_waitcnt vmcnt(3)" ::: "memory"); }
        else             { asm volatile("s_waitcnt vmcnt(0)" ::: "memory"); }
        __builtin_amdgcn_s_barrier();
        cb = (cb + 1 == 3) ? 0 : cb + 1;
    }

    const int rbase = (lane >> 4) * 4;
    #pragma unroll
    for (int m = 0; m < 4; ++m) {
        #pragma unroll
        for (int n = 0; n < 2; ++n) {
            #pragma unroll
            for (int g = 0; g < 4; ++g) {
                int gm = m0 + wr * 64 + m * 16 + rbase + g;
                int gn = n0 + wc * 32 + n * 16 + row_l;
                outp[(long)gm * DM + gn] = acc[m][n][g] + bo[gn];
            }
        }
    }
}

// ---------------------------------------------------------------------------
// Flash attention v8 (unchanged from round 13): 512 thr pair blocks,
// 3-buffer K/V ring (counted vmcnt(2)), XOR-packed Ps, diagonal-only mask
// fast path, CU-balanced pair map, static-shift exp2 softmax.
// ---------------------------------------------------------------------------
__global__ __launch_bounds__(512, 4) void attn_kernel(
    const bf16* __restrict__ Qb, const bf16* __restrict__ Kb,
    const bf16* __restrict__ Vtb, const float* __restrict__ biasT,
    bf16* __restrict__ AO)
{
    __shared__ __align__(16) bf16 Ks[3][64 * 64];
    __shared__ __align__(16) bf16 Vs[3][64 * 64];
    __shared__ __align__(16) bf16 Ps[8][16 * 64];
    __shared__ float biasS[SEQ_];

    int t = threadIdx.x;
    int lane = t & 63, w = t >> 6;

    int bid = blockIdx.x;
    int xcd = bid & 7;
    int rest = bid >> 3;
    int g = xcd * 8 + (rest & 7);
    int pe = rest >> 3;
    int p = (pe < 4) ? pe : 11 - pe;
    int qt_hi = 15 - p;
    int h = g & 15, b = g >> 4;

    int qtw = (w < 4) ? p : qt_hi;
    int row0 = qtw * 64 + (w & 3) * 16;

    int row_l = lane & 15;
    int ksl = (lane >> 4) * 8;
    int rbase = (lane >> 4) * 4;

    const bf16* Kbase = Kb + (long)g * SEQ_ * HD;
    const bf16* Vbase = Vtb + (long)g * HD * SEQ_;

    auto stageKV = [&](int jt) {
        int sl = jt % 3;
        int e = t * 8;
        int r = e >> 6;
        int csw = ((((e >> 3) & 7) ^ (r & 7)) << 3);
        gl_lds16(Kbase + (long)(jt * 64 + r) * HD + csw, &Ks[sl][0] + w * 512);
        gl_lds16(Vbase + (long)r * SEQ_ + jt * 64 + csw, &Vs[sl][0] + w * 512);
    };

    stageKV(0);
    stageKV(1);
    if (t < 256)
        ((float4*)biasS)[t] = ((const float4*)(biasT + (long)h * SEQ_))[t];

    const bf16* Qp = Qb + ((long)g * SEQ_ + row0) * HD;
    bf16x8 qf0 = *(const bf16x8*)&Qp[row_l * HD + ksl];
    bf16x8 qf1 = *(const bf16x8*)&Qp[row_l * HD + 32 + ksl];

    f32x4 oacc[4] = {};
    float lsum[4] = {0.f, 0.f, 0.f, 0.f};
    int ir[4];
    #pragma unroll
    for (int q = 0; q < 4; ++q) ir[q] = row0 + rbase + q;

    __syncthreads();

    char* psw = (char*)&Ps[w][0];
    int prswz = (row_l & 7) << 4;

    for (int jt = 0; jt <= qt_hi; ++jt) {
        if (jt < qt_hi) { asm volatile("s_waitcnt vmcnt(2)" ::: "memory"); }
        else            { asm volatile("s_waitcnt vmcnt(0)" ::: "memory"); }
        __builtin_amdgcn_s_barrier();
        if (jt + 2 <= qt_hi) stageKV(jt + 2);

        if (jt <= qtw) {
            int sl = jt % 3;
            const bf16* kb_ = &Ks[sl][0];
            const bf16* vb_ = &Vs[sl][0];

            f32x4 s[4] = {};
            __builtin_amdgcn_s_setprio(1);
            #pragma unroll
            for (int f = 0; f < 4; ++f) {
                int ra = f * 16 + row_l;
                int a0 = (ra * 64 + ksl)      ^ ((ra & 7) << 3);
                int a1 = (ra * 64 + 32 + ksl) ^ ((ra & 7) << 3);
                bf16x8 kf0 = *(const bf16x8*)&kb_[a0];
                bf16x8 kf1 = *(const bf16x8*)&kb_[a1];
                s[f] = __builtin_amdgcn_mfma_f32_16x16x32_bf16(qf0, kf0, s[f], 0,0,0);
                s[f] = __builtin_amdgcn_mfma_f32_16x16x32_bf16(qf1, kf1, s[f], 0,0,0);
            }
            __builtin_amdgcn_s_setprio(0);

            if (jt < qtw) {
                #pragma unroll
                for (int f = 0; f < 4; ++f) {
                    int j = jt * 64 + f * 16 + row_l;
                    #pragma unroll
                    for (int q = 0; q < 4; ++q) {
                        float sv = s[f][q] + biasS[ir[q] - j];
                        float pexp = exp2f(sv);
                        lsum[q] += pexp;
                        int pr = rbase + q;
                        int byte = pr * 128 + ((((f*16 + row_l) * 2)) ^ ((pr & 7) << 4));
                        *(bf16*)(psw + byte) = (bf16)pexp;
                    }
                }
            } else {
                #pragma unroll
                for (int f = 0; f < 4; ++f) {
                    int j = jt * 64 + f * 16 + row_l;
                    #pragma unroll
                    for (int q = 0; q < 4; ++q) {
                        float sv = (j <= ir[q]) ? (s[f][q] + biasS[ir[q] - j]) : -1e30f;
                        float pexp = exp2f(sv);
                        lsum[q] += pexp;
                        int pr = rbase + q;
                        int byte = pr * 128 + ((((f*16 + row_l) * 2)) ^ ((pr & 7) << 4));
                        *(bf16*)(psw + byte) = (bf16)pexp;
                    }
                }
            }
            bf16x8 pf0 = *(const bf16x8*)(psw + row_l * 128 + ((ksl * 2) ^ prswz));
            bf16x8 pf1 = *(const bf16x8*)(psw + row_l * 128 + ((64 + ksl * 2) ^ prswz));

            __builtin_amdgcn_s_setprio(1);
            #pragma unroll
            for (int db = 0; db < 4; ++db) {
                int ra = db * 16 + row_l;
                int a0 = (ra * 64 + ksl)      ^ ((ra & 7) << 3);
                int a1 = (ra * 64 + 32 + ksl) ^ ((ra & 7) << 3);
                bf16x8 vf0 = *(const bf16x8*)&vb_[a0];
                bf16x8 vf1 = *(const bf16x8*)&vb_[a1];
                oacc[db] = __builtin_amdgcn_mfma_f32_16x16x32_bf16(pf0, vf0, oacc[db], 0,0,0);
                oacc[db] = __builtin_amdgcn_mfma_f32_16x16x32_bf16(pf1, vf1, oacc[db], 0,0,0);
            }
            __builtin_amdgcn_s_setprio(0);
        }
    }

    #pragma unroll
    for (int q = 0; q < 4; ++q) {
        float l = lsum[q];
        #pragma unroll
        for (int off = 1; off < 16; off <<= 1) l += __shfl_xor(l, off);
        float inv = 1.0f / l;
        long base = ((long)(b * SEQ_ + ir[q])) * DM + h * HD;
        #pragma unroll
        for (int db = 0; db < 4; ++db)
            AO[base + db * 16 + row_l] = (bf16)(oacc[db][q] * inv);
    }
}

// ---------------------------------------------------------------------------
extern "C" void kernel_launch(void* const* d_in, const int* in_sizes, int n_in,
                              void* d_out, int out_size, void* d_ws, size_t ws_size,
                              hipStream_t stream)
{
    const float* x   = (const float*)d_in[0];
    const float* Wq  = (const float*)d_in[1];
    const float* bq  = (const float*)d_in[2];
    const float* Wk  = (const float*)d_in[3];
    const float* bk  = (const float*)d_in[4];
    const float* Wv  = (const float*)d_in[5];
    const float* bv  = (const float*)d_in[6];
    const float* Wo  = (const float*)d_in[7];
    const float* bo  = (const float*)d_in[8];
    const float* rel = (const float*)d_in[9];
    float* out = (float*)d_out;

    char* ws = (char*)d_ws;
    bf16* xb    = (bf16*)ws;  ws += (size_t)B_*SEQ_*DM * 2;
    bf16* wqkvb = (bf16*)ws;  ws += (size_t)3*DM*DM * 2;
    bf16* wob   = (bf16*)ws;  ws += (size_t)DM*DM * 2;
    float* biasT= (float*)ws; ws += (size_t)H_*SEQ_ * 4;
    bf16* Qb    = (bf16*)ws;  ws += (size_t)B_*H_*SEQ_*HD * 2;
    bf16* Kb2   = (bf16*)ws;  ws += (size_t)B_*H_*SEQ_*HD * 2;
    bf16* Vtb   = (bf16*)ws;  ws += (size_t)B_*H_*SEQ_*HD * 2;
    bf16* AO    = (bf16*)ws;  ws += (size_t)B_*SEQ_*DM * 2;

    prep_kernel<<<2048, 256, 0, stream>>>(x, Wq, Wk, Wv, Wo, rel,
                                          xb, wqkvb, wob, biasT);

    // QKV: M=4096, N=3072 -> 16 x 12 = 192 blocks of 256x256, NT=16
    gemm8q<16><<<192, 512, 0, stream>>>(
        xb, wqkvb, Qb, Kb2, Vtb, bq, bk, bv);

    attn_kernel<<<512, 512, 0, stream>>>(Qb, Kb2, Vtb, biasT, AO);

    // out-proj: M=4096, N=1024 -> 32 x 16 = 512 blocks of 128x64
    gemm_ring_o<32><<<512, 256, 0, stream>>>(AO, wob, out, bo);
}